// Round 1
// baseline (1823.547 us; speedup 1.0000x reference)
//
#include <hip/hip_runtime.h>

#define F 128
#define F3 384
#define NRBF 20
#define NPB 16   // nodes per block in phi kernel

// ---------------- Kernel: transpose Wr [384][20] -> WrT [20][384] ----------------
__global__ void transpose_wr(const float* __restrict__ Wr, float* __restrict__ WrT) {
    int idx = blockIdx.x * blockDim.x + threadIdx.x;
    if (idx < F3 * NRBF) {
        int f = idx / NRBF, r = idx % NRBF;
        WrT[r * F3 + f] = Wr[idx];
    }
}

// ---------------- Kernel: init d_out with inputs (residual base) ----------------
__global__ void init_out(const float* __restrict__ sf, const float* __restrict__ vf,
                         float* __restrict__ out, int n_scalar, int n_total) {
    int i = blockIdx.x * blockDim.x + threadIdx.x;   // float4 index
    int n4 = n_total >> 2;
    if (i < n4) {
        float4 v;
        int base = i << 2;
        if (base < n_scalar) v = ((const float4*)sf)[i];
        else                 v = ((const float4*)vf)[i - (n_scalar >> 2)];
        ((float4*)out)[i] = v;
    }
}

// ---------------- Kernel: per-node MLP phi = W2 @ silu(W1 @ x + b1) + b2 ----------------
__launch_bounds__(256)
__global__ void phi_kernel(const float* __restrict__ sf,
                           const float* __restrict__ W1, const float* __restrict__ b1,
                           const float* __restrict__ W2, const float* __restrict__ b2,
                           float* __restrict__ phi, int n_nodes) {
    __shared__ float xs[NPB][F];
    __shared__ float hs[NPB][F];
    int tid = threadIdx.x;
    int nb = blockIdx.x * NPB;

    // stage x tile (zero-fill out-of-range nodes)
    for (int t = tid; t < NPB * F / 4; t += 256) {
        int n  = t / (F / 4);
        int k4 = t % (F / 4);
        float4 v = make_float4(0.f, 0.f, 0.f, 0.f);
        if (nb + n < n_nodes) v = ((const float4*)(sf + (size_t)(nb + n) * F))[k4];
        ((float4*)&xs[n][0])[k4] = v;
    }
    __syncthreads();

    // h = silu(x @ W1^T + b1): thread (half,f) does 8 nodes
    {
        int f = tid & (F - 1);
        int half = tid >> 7;  // 0 or 1
        float acc[8];
#pragma unroll
        for (int nn = 0; nn < 8; nn++) acc[nn] = 0.f;
        const float* w1row = W1 + (size_t)f * F;
        for (int k = 0; k < F; k++) {
            float w = w1row[k];
#pragma unroll
            for (int nn = 0; nn < 8; nn++)
                acc[nn] += xs[half * 8 + nn][k] * w;
        }
        float b = b1[f];
#pragma unroll
        for (int nn = 0; nn < 8; nn++) {
            float v = acc[nn] + b;
            hs[half * 8 + nn][f] = v / (1.f + __expf(-v));   // silu
        }
    }
    __syncthreads();

    // phi = h @ W2^T + b2
    for (int f = tid; f < F3; f += 256) {
        float acc[NPB];
#pragma unroll
        for (int n = 0; n < NPB; n++) acc[n] = 0.f;
        const float* w2row = W2 + (size_t)f * F;
        for (int k = 0; k < F; k++) {
            float w = w2row[k];
#pragma unroll
            for (int n = 0; n < NPB; n++)
                acc[n] += hs[n][k] * w;
        }
        float b = b2[f];
        for (int n = 0; n < NPB; n++) {
            if (nb + n < n_nodes)
                phi[(size_t)(nb + n) * F3 + f] = acc[n] + b;
        }
    }
}

// ---------------- Kernel: per-edge messages + atomic scatter ----------------
__launch_bounds__(256)
__global__ void edge_kernel(const int* __restrict__ idx_i, const int* __restrict__ idx_j,
                            const float* __restrict__ rel_dir, const float* __restrict__ rdc,
                            const float* __restrict__ rbf,
                            const float* __restrict__ vf,
                            const float* __restrict__ WrT, const float* __restrict__ br,
                            const float* __restrict__ phi,
                            float* __restrict__ out_s, float* __restrict__ out_v,
                            int n_edges) {
    int lane = threadIdx.x & 63;
    int e = (int)((blockIdx.x * (unsigned)blockDim.x + threadIdx.x) >> 6);  // one wave per edge
    if (e >= n_edges) return;

    int i = idx_i[e], j = idx_j[e];
    float rd = rdc[e];
    float d0 = rel_dir[e * 3 + 0], d1 = rel_dir[e * 3 + 1], d2 = rel_dir[e * 3 + 2];

    float rb[NRBF];
#pragma unroll
    for (int r = 0; r < NRBF; r++) rb[r] = rbf[(size_t)e * NRBF + r];

    // pw[q] = phi[j][f] * (rbf @ WrT + br)[f] * rdc,  f = lane + 64q
    const float* pj = phi + (size_t)j * F3;
    float pw[6];
#pragma unroll
    for (int q = 0; q < 6; q++) {
        int f = lane + 64 * q;
        float acc = br[f];
#pragma unroll
        for (int r = 0; r < NRBF; r++)
            acc += rb[r] * WrT[r * F3 + f];
        pw[q] = acc * rd * pj[f];
    }

    // scalar residual: features [128,256)
    atomicAdd(&out_s[(size_t)i * F + lane],       pw[2]);
    atomicAdd(&out_s[(size_t)i * F + lane + 64],  pw[3]);

    // vector residual
    const float* vfj = vf + (size_t)j * F * 3;
    float* ovi = out_v + (size_t)i * F * 3;
#pragma unroll
    for (int h = 0; h < 2; h++) {
        int f = lane + 64 * h;
        float vv = pw[h];
        float vs = pw[4 + h];
        atomicAdd(&ovi[f * 3 + 0], vfj[f * 3 + 0] * vv + vs * d0);
        atomicAdd(&ovi[f * 3 + 1], vfj[f * 3 + 1] * vv + vs * d1);
        atomicAdd(&ovi[f * 3 + 2], vfj[f * 3 + 2] * vv + vs * d2);
    }
}

// ---------------- Fallback (ws too small): phi recomputed per edge ----------------
__launch_bounds__(256)
__global__ void edge_fused_kernel(const int* __restrict__ idx_i, const int* __restrict__ idx_j,
                                  const float* __restrict__ rel_dir, const float* __restrict__ rdc,
                                  const float* __restrict__ rbf,
                                  const float* __restrict__ sf, const float* __restrict__ vf,
                                  const float* __restrict__ W1, const float* __restrict__ b1,
                                  const float* __restrict__ W2, const float* __restrict__ b2,
                                  const float* __restrict__ Wr, const float* __restrict__ br,
                                  float* __restrict__ out_s, float* __restrict__ out_v,
                                  int n_edges) {
    __shared__ float xs[4][F];
    __shared__ float hsm[4][F];
    int wv = threadIdx.x >> 6, lane = threadIdx.x & 63;
    int e = blockIdx.x * 4 + wv;
    bool valid = e < n_edges;
    int ec = valid ? e : 0;

    int i = idx_i[ec], j = idx_j[ec];
    float rd = rdc[ec];
    float d0 = rel_dir[ec * 3 + 0], d1 = rel_dir[ec * 3 + 1], d2 = rel_dir[ec * 3 + 2];

    const float* xrow = sf + (size_t)j * F;
    xs[wv][lane] = xrow[lane];
    xs[wv][lane + 64] = xrow[lane + 64];
    __syncthreads();

#pragma unroll
    for (int hh = 0; hh < 2; hh++) {
        int f = lane + 64 * hh;
        float acc = b1[f];
        for (int k = 0; k < F; k++) acc += xs[wv][k] * W1[(size_t)f * F + k];
        hsm[wv][f] = acc / (1.f + __expf(-acc));
    }
    __syncthreads();

    float rb[NRBF];
#pragma unroll
    for (int r = 0; r < NRBF; r++) rb[r] = rbf[(size_t)ec * NRBF + r];

    float pw[6];
#pragma unroll
    for (int q = 0; q < 6; q++) {
        int f = lane + 64 * q;
        float accW = br[f];
#pragma unroll
        for (int r = 0; r < NRBF; r++) accW += rb[r] * Wr[(size_t)f * NRBF + r];
        float accP = b2[f];
        for (int k = 0; k < F; k++) accP += hsm[wv][k] * W2[(size_t)f * F + k];
        pw[q] = accW * rd * accP;
    }

    if (valid) {
        atomicAdd(&out_s[(size_t)i * F + lane],      pw[2]);
        atomicAdd(&out_s[(size_t)i * F + lane + 64], pw[3]);
        const float* vfj = vf + (size_t)j * F * 3;
        float* ovi = out_v + (size_t)i * F * 3;
#pragma unroll
        for (int hh = 0; hh < 2; hh++) {
            int f = lane + 64 * hh;
            float vv = pw[hh], vs = pw[4 + hh];
            atomicAdd(&ovi[f * 3 + 0], vfj[f * 3 + 0] * vv + vs * d0);
            atomicAdd(&ovi[f * 3 + 1], vfj[f * 3 + 1] * vv + vs * d1);
            atomicAdd(&ovi[f * 3 + 2], vfj[f * 3 + 2] * vv + vs * d2);
        }
    }
}

extern "C" void kernel_launch(void* const* d_in, const int* in_sizes, int n_in,
                              void* d_out, int out_size, void* d_ws, size_t ws_size,
                              hipStream_t stream) {
    const int*   idx_i  = (const int*)d_in[0];
    const int*   idx_j  = (const int*)d_in[1];
    const float* rel_dir = (const float*)d_in[2];
    const float* rdc    = (const float*)d_in[3];
    const float* rbf    = (const float*)d_in[4];
    const float* sf     = (const float*)d_in[5];
    const float* vf     = (const float*)d_in[6];
    const float* W1     = (const float*)d_in[7];
    const float* b1     = (const float*)d_in[8];
    const float* W2     = (const float*)d_in[9];
    const float* b2     = (const float*)d_in[10];
    const float* Wr     = (const float*)d_in[11];
    const float* br     = (const float*)d_in[12];

    int E = in_sizes[0];
    int N = in_sizes[5] / F;

    float* out_s = (float*)d_out;
    float* out_v = out_s + (size_t)N * F;

    // 1) residual base: out = concat(scalar_features, vector_features)
    int n_scalar = N * F;
    int n_total  = N * F * 4;  // F + 3F floats per node
    int n4 = n_total / 4;
    init_out<<<(n4 + 255) / 256, 256, 0, stream>>>(sf, vf, (float*)d_out, n_scalar, n_total);

    size_t phi_off = (size_t)F3 * NRBF * sizeof(float);       // WrT at ws[0]
    size_t need = phi_off + (size_t)N * F3 * sizeof(float);   // + phi buffer

    if (ws_size >= need) {
        float* WrT = (float*)d_ws;
        float* phi = (float*)((char*)d_ws + phi_off);
        transpose_wr<<<(F3 * NRBF + 255) / 256, 256, 0, stream>>>(Wr, WrT);
        phi_kernel<<<(N + NPB - 1) / NPB, 256, 0, stream>>>(sf, W1, b1, W2, b2, phi, N);
        edge_kernel<<<(E + 3) / 4, 256, 0, stream>>>(idx_i, idx_j, rel_dir, rdc, rbf,
                                                     vf, WrT, br, phi, out_s, out_v, E);
    } else {
        edge_fused_kernel<<<(E + 3) / 4, 256, 0, stream>>>(idx_i, idx_j, rel_dir, rdc, rbf,
                                                           sf, vf, W1, b1, W2, b2, Wr, br,
                                                           out_s, out_v, E);
    }
}

// Round 2
// 494.202 us; speedup vs baseline: 3.6899x; 3.6899x over previous
//
#include <hip/hip_runtime.h>

#define F 128
#define F3 384
#define NRBF 20
#define NPB 16   // nodes per block in phi kernel

// ---------------- transpose Wr [384][20] -> WrT [20][384] ----------------
__global__ void transpose_wr(const float* __restrict__ Wr, float* __restrict__ WrT) {
    int idx = blockIdx.x * blockDim.x + threadIdx.x;
    if (idx < F3 * NRBF) {
        int f = idx / NRBF, r = idx % NRBF;
        WrT[r * F3 + f] = Wr[idx];
    }
}

// ---------------- init d_out with inputs (fallback paths only) ----------------
__global__ void init_out(const float* __restrict__ sf, const float* __restrict__ vf,
                         float* __restrict__ out, int n_scalar, int n_total) {
    int i = blockIdx.x * blockDim.x + threadIdx.x;
    int n4 = n_total >> 2;
    if (i < n4) {
        float4 v;
        int base = i << 2;
        if (base < n_scalar) v = ((const float4*)sf)[i];
        else                 v = ((const float4*)vf)[i - (n_scalar >> 2)];
        ((float4*)out)[i] = v;
    }
}

// ---------------- per-node MLP phi = W2 @ silu(W1 @ x + b1) + b2 ----------------
__launch_bounds__(256)
__global__ void phi_kernel(const float* __restrict__ sf,
                           const float* __restrict__ W1, const float* __restrict__ b1,
                           const float* __restrict__ W2, const float* __restrict__ b2,
                           float* __restrict__ phi, int n_nodes) {
    __shared__ float xs[NPB][F];
    __shared__ float hs[NPB][F];
    int tid = threadIdx.x;
    int nb = blockIdx.x * NPB;

    for (int t = tid; t < NPB * F / 4; t += 256) {
        int n  = t / (F / 4);
        int k4 = t % (F / 4);
        float4 v = make_float4(0.f, 0.f, 0.f, 0.f);
        if (nb + n < n_nodes) v = ((const float4*)(sf + (size_t)(nb + n) * F))[k4];
        ((float4*)&xs[n][0])[k4] = v;
    }
    __syncthreads();

    {
        int f = tid & (F - 1);
        int half = tid >> 7;
        float acc[8];
#pragma unroll
        for (int nn = 0; nn < 8; nn++) acc[nn] = 0.f;
        const float* w1row = W1 + (size_t)f * F;
        for (int k = 0; k < F; k++) {
            float w = w1row[k];
#pragma unroll
            for (int nn = 0; nn < 8; nn++)
                acc[nn] += xs[half * 8 + nn][k] * w;
        }
        float b = b1[f];
#pragma unroll
        for (int nn = 0; nn < 8; nn++) {
            float v = acc[nn] + b;
            hs[half * 8 + nn][f] = v / (1.f + __expf(-v));
        }
    }
    __syncthreads();

    for (int f = tid; f < F3; f += 256) {
        float acc[NPB];
#pragma unroll
        for (int n = 0; n < NPB; n++) acc[n] = 0.f;
        const float* w2row = W2 + (size_t)f * F;
        for (int k = 0; k < F; k++) {
            float w = w2row[k];
#pragma unroll
            for (int n = 0; n < NPB; n++)
                acc[n] += hs[n][k] * w;
        }
        float b = b2[f];
        for (int n = 0; n < NPB; n++) {
            if (nb + n < n_nodes)
                phi[(size_t)(nb + n) * F3 + f] = acc[n] + b;
        }
    }
}

// ---------------- CSR build: zero, histogram, scan, scatter ----------------
__global__ void zero_counts(int* __restrict__ counts, int n) {
    int i = blockIdx.x * blockDim.x + threadIdx.x;
    if (i < n) counts[i] = 0;
}

__global__ void hist_kernel(const int* __restrict__ idx_i, int* __restrict__ counts, int n_edges) {
    int e = blockIdx.x * blockDim.x + threadIdx.x;
    if (e < n_edges) atomicAdd(&counts[idx_i[e]], 1);
}

__launch_bounds__(1024)
__global__ void scan_kernel(const int* __restrict__ counts, int* __restrict__ row_start,
                            int* __restrict__ cursor, int n) {
    __shared__ int partial[1024];
    int t = threadIdx.x;
    int C = (n + 1023) / 1024;
    int beg = t * C;
    int end = min(beg + C, n);
    int sum = 0;
    for (int i = beg; i < end; i++) sum += counts[i];
    partial[t] = sum;
    __syncthreads();
    for (int off = 1; off < 1024; off <<= 1) {
        int v = (t >= off) ? partial[t - off] : 0;
        __syncthreads();
        partial[t] += v;
        __syncthreads();
    }
    int base = (t == 0) ? 0 : partial[t - 1];
    for (int i = beg; i < end; i++) {
        row_start[i] = base;
        cursor[i] = base;
        base += counts[i];
    }
    if (t == 1023) row_start[n] = partial[1023];
}

__global__ void scatter_kernel(const int* __restrict__ idx_i, int* __restrict__ cursor,
                               int* __restrict__ edge_order, int n_edges) {
    int e = blockIdx.x * blockDim.x + threadIdx.x;
    if (e < n_edges) {
        int p = atomicAdd(&cursor[idx_i[e]], 1);
        edge_order[p] = e;
    }
}

// ---------------- gather: one wave per destination node, zero atomics ----------------
__launch_bounds__(256)
__global__ void gather_kernel(const int* __restrict__ idx_j,
                              const float* __restrict__ rel_dir, const float* __restrict__ rdc,
                              const float* __restrict__ rbf,
                              const float* __restrict__ sf, const float* __restrict__ vf,
                              const float* __restrict__ WrT, const float* __restrict__ br,
                              const float* __restrict__ phi,
                              const int* __restrict__ row_start, const int* __restrict__ edge_order,
                              float* __restrict__ out_s, float* __restrict__ out_v,
                              int n_nodes) {
    int lane = threadIdx.x & 63;
    int node = blockIdx.x * 4 + (threadIdx.x >> 6);
    if (node >= n_nodes) return;

    // hoist RBF weight columns for this lane's 6 features into registers
    float wr[6][NRBF];
#pragma unroll
    for (int r = 0; r < NRBF; r++) {
#pragma unroll
        for (int q = 0; q < 6; q++)
            wr[q][r] = WrT[r * F3 + lane + 64 * q];
    }
    float brv[6];
#pragma unroll
    for (int q = 0; q < 6; q++) brv[q] = br[lane + 64 * q];

    float acc_s0 = 0.f, acc_s1 = 0.f;
    float av[2][3];
#pragma unroll
    for (int h = 0; h < 2; h++)
#pragma unroll
        for (int c = 0; c < 3; c++) av[h][c] = 0.f;

    int beg = row_start[node];
    int end = row_start[node + 1];

    for (int k = beg; k < end; k++) {
        int e = edge_order[k];
        e = __builtin_amdgcn_readfirstlane(e);
        int j = idx_j[e];
        j = __builtin_amdgcn_readfirstlane(j);
        float rd = rdc[e];
        float d0 = rel_dir[e * 3 + 0], d1 = rel_dir[e * 3 + 1], d2 = rel_dir[e * 3 + 2];

        float rb[NRBF];
#pragma unroll
        for (int r = 0; r < NRBF; r++) rb[r] = rbf[(size_t)e * NRBF + r];

        const float* pj = phi + (size_t)j * F3;
        float pjv[6];
#pragma unroll
        for (int q = 0; q < 6; q++) pjv[q] = pj[lane + 64 * q];

        float pw[6];
#pragma unroll
        for (int q = 0; q < 6; q++) {
            float a = brv[q];
#pragma unroll
            for (int r = 0; r < NRBF; r++) a += rb[r] * wr[q][r];
            pw[q] = a * rd * pjv[q];
        }

        acc_s0 += pw[2];
        acc_s1 += pw[3];

        const float* vfj = vf + (size_t)j * F * 3;
#pragma unroll
        for (int h = 0; h < 2; h++) {
            int f = lane + 64 * h;
            float vv = pw[h];
            float vs = pw[4 + h];
            av[h][0] += vfj[f * 3 + 0] * vv + vs * d0;
            av[h][1] += vfj[f * 3 + 1] * vv + vs * d1;
            av[h][2] += vfj[f * 3 + 2] * vv + vs * d2;
        }
    }

    // single non-atomic write: out = input + residual
    const float* sfi = sf + (size_t)node * F;
    float* osi = out_s + (size_t)node * F;
    osi[lane]      = sfi[lane]      + acc_s0;
    osi[lane + 64] = sfi[lane + 64] + acc_s1;

    const float* vfi = vf + (size_t)node * F * 3;
    float* ovi = out_v + (size_t)node * F * 3;
#pragma unroll
    for (int h = 0; h < 2; h++) {
        int f = lane + 64 * h;
#pragma unroll
        for (int c = 0; c < 3; c++)
            ovi[f * 3 + c] = vfi[f * 3 + c] + av[h][c];
    }
}

// ---------------- fallback: per-edge atomics (R1 kernel) ----------------
__launch_bounds__(256)
__global__ void edge_kernel(const int* __restrict__ idx_i, const int* __restrict__ idx_j,
                            const float* __restrict__ rel_dir, const float* __restrict__ rdc,
                            const float* __restrict__ rbf,
                            const float* __restrict__ vf,
                            const float* __restrict__ WrT, const float* __restrict__ br,
                            const float* __restrict__ phi,
                            float* __restrict__ out_s, float* __restrict__ out_v,
                            int n_edges) {
    int lane = threadIdx.x & 63;
    int e = (int)((blockIdx.x * (unsigned)blockDim.x + threadIdx.x) >> 6);
    if (e >= n_edges) return;

    int i = idx_i[e], j = idx_j[e];
    float rd = rdc[e];
    float d0 = rel_dir[e * 3 + 0], d1 = rel_dir[e * 3 + 1], d2 = rel_dir[e * 3 + 2];

    float rb[NRBF];
#pragma unroll
    for (int r = 0; r < NRBF; r++) rb[r] = rbf[(size_t)e * NRBF + r];

    const float* pj = phi + (size_t)j * F3;
    float pw[6];
#pragma unroll
    for (int q = 0; q < 6; q++) {
        int f = lane + 64 * q;
        float acc = br[f];
#pragma unroll
        for (int r = 0; r < NRBF; r++)
            acc += rb[r] * WrT[r * F3 + f];
        pw[q] = acc * rd * pj[f];
    }

    atomicAdd(&out_s[(size_t)i * F + lane],       pw[2]);
    atomicAdd(&out_s[(size_t)i * F + lane + 64],  pw[3]);

    const float* vfj = vf + (size_t)j * F * 3;
    float* ovi = out_v + (size_t)i * F * 3;
#pragma unroll
    for (int h = 0; h < 2; h++) {
        int f = lane + 64 * h;
        float vv = pw[h];
        float vs = pw[4 + h];
        atomicAdd(&ovi[f * 3 + 0], vfj[f * 3 + 0] * vv + vs * d0);
        atomicAdd(&ovi[f * 3 + 1], vfj[f * 3 + 1] * vv + vs * d1);
        atomicAdd(&ovi[f * 3 + 2], vfj[f * 3 + 2] * vv + vs * d2);
    }
}

// ---------------- fallback (tiny ws): fused recompute ----------------
__launch_bounds__(256)
__global__ void edge_fused_kernel(const int* __restrict__ idx_i, const int* __restrict__ idx_j,
                                  const float* __restrict__ rel_dir, const float* __restrict__ rdc,
                                  const float* __restrict__ rbf,
                                  const float* __restrict__ sf, const float* __restrict__ vf,
                                  const float* __restrict__ W1, const float* __restrict__ b1,
                                  const float* __restrict__ W2, const float* __restrict__ b2,
                                  const float* __restrict__ Wr, const float* __restrict__ br,
                                  float* __restrict__ out_s, float* __restrict__ out_v,
                                  int n_edges) {
    __shared__ float xs[4][F];
    __shared__ float hsm[4][F];
    int wv = threadIdx.x >> 6, lane = threadIdx.x & 63;
    int e = blockIdx.x * 4 + wv;
    bool valid = e < n_edges;
    int ec = valid ? e : 0;

    int i = idx_i[ec], j = idx_j[ec];
    float rd = rdc[ec];
    float d0 = rel_dir[ec * 3 + 0], d1 = rel_dir[ec * 3 + 1], d2 = rel_dir[ec * 3 + 2];

    const float* xrow = sf + (size_t)j * F;
    xs[wv][lane] = xrow[lane];
    xs[wv][lane + 64] = xrow[lane + 64];
    __syncthreads();

#pragma unroll
    for (int hh = 0; hh < 2; hh++) {
        int f = lane + 64 * hh;
        float acc = b1[f];
        for (int k = 0; k < F; k++) acc += xs[wv][k] * W1[(size_t)f * F + k];
        hsm[wv][f] = acc / (1.f + __expf(-acc));
    }
    __syncthreads();

    float rb[NRBF];
#pragma unroll
    for (int r = 0; r < NRBF; r++) rb[r] = rbf[(size_t)ec * NRBF + r];

    float pw[6];
#pragma unroll
    for (int q = 0; q < 6; q++) {
        int f = lane + 64 * q;
        float accW = br[f];
#pragma unroll
        for (int r = 0; r < NRBF; r++) accW += rb[r] * Wr[(size_t)f * NRBF + r];
        float accP = b2[f];
        for (int k = 0; k < F; k++) accP += hsm[wv][k] * W2[(size_t)f * F + k];
        pw[q] = accW * rd * accP;
    }

    if (valid) {
        atomicAdd(&out_s[(size_t)i * F + lane],      pw[2]);
        atomicAdd(&out_s[(size_t)i * F + lane + 64], pw[3]);
        const float* vfj = vf + (size_t)j * F * 3;
        float* ovi = out_v + (size_t)i * F * 3;
#pragma unroll
        for (int hh = 0; hh < 2; hh++) {
            int f = lane + 64 * hh;
            float vv = pw[hh], vs = pw[4 + hh];
            atomicAdd(&ovi[f * 3 + 0], vfj[f * 3 + 0] * vv + vs * d0);
            atomicAdd(&ovi[f * 3 + 1], vfj[f * 3 + 1] * vv + vs * d1);
            atomicAdd(&ovi[f * 3 + 2], vfj[f * 3 + 2] * vv + vs * d2);
        }
    }
}

extern "C" void kernel_launch(void* const* d_in, const int* in_sizes, int n_in,
                              void* d_out, int out_size, void* d_ws, size_t ws_size,
                              hipStream_t stream) {
    const int*   idx_i   = (const int*)d_in[0];
    const int*   idx_j   = (const int*)d_in[1];
    const float* rel_dir = (const float*)d_in[2];
    const float* rdc     = (const float*)d_in[3];
    const float* rbf     = (const float*)d_in[4];
    const float* sf      = (const float*)d_in[5];
    const float* vf      = (const float*)d_in[6];
    const float* W1      = (const float*)d_in[7];
    const float* b1      = (const float*)d_in[8];
    const float* W2      = (const float*)d_in[9];
    const float* b2      = (const float*)d_in[10];
    const float* Wr      = (const float*)d_in[11];
    const float* br      = (const float*)d_in[12];

    int E = in_sizes[0];
    int N = in_sizes[5] / F;

    float* out_s = (float*)d_out;
    float* out_v = out_s + (size_t)N * F;

    // workspace layout (256B-aligned slabs)
    size_t off = 0;
    auto slab = [&](size_t bytes) { size_t o = off; off = (off + bytes + 255) & ~(size_t)255; return o; };
    size_t o_wrt   = slab((size_t)F3 * NRBF * sizeof(float));
    size_t o_phi   = slab((size_t)N * F3 * sizeof(float));
    size_t need_phi = off;
    size_t o_cnt   = slab((size_t)N * sizeof(int));
    size_t o_row   = slab((size_t)(N + 1) * sizeof(int));
    size_t o_cur   = slab((size_t)N * sizeof(int));
    size_t o_ord   = slab((size_t)E * sizeof(int));
    size_t need_full = off;

    if (ws_size >= need_full) {
        float* WrT       = (float*)((char*)d_ws + o_wrt);
        float* phi       = (float*)((char*)d_ws + o_phi);
        int*   counts    = (int*)((char*)d_ws + o_cnt);
        int*   row_start = (int*)((char*)d_ws + o_row);
        int*   cursor    = (int*)((char*)d_ws + o_cur);
        int*   edge_ord  = (int*)((char*)d_ws + o_ord);

        transpose_wr<<<(F3 * NRBF + 255) / 256, 256, 0, stream>>>(Wr, WrT);
        phi_kernel<<<(N + NPB - 1) / NPB, 256, 0, stream>>>(sf, W1, b1, W2, b2, phi, N);
        zero_counts<<<(N + 255) / 256, 256, 0, stream>>>(counts, N);
        hist_kernel<<<(E + 255) / 256, 256, 0, stream>>>(idx_i, counts, E);
        scan_kernel<<<1, 1024, 0, stream>>>(counts, row_start, cursor, N);
        scatter_kernel<<<(E + 255) / 256, 256, 0, stream>>>(idx_i, cursor, edge_ord, E);
        gather_kernel<<<(N + 3) / 4, 256, 0, stream>>>(idx_j, rel_dir, rdc, rbf, sf, vf,
                                                       WrT, br, phi, row_start, edge_ord,
                                                       out_s, out_v, N);
    } else {
        int n_scalar = N * F;
        int n_total  = N * F * 4;
        int n4 = n_total / 4;
        init_out<<<(n4 + 255) / 256, 256, 0, stream>>>(sf, vf, (float*)d_out, n_scalar, n_total);
        if (ws_size >= need_phi) {
            float* WrT = (float*)((char*)d_ws + o_wrt);
            float* phi = (float*)((char*)d_ws + o_phi);
            transpose_wr<<<(F3 * NRBF + 255) / 256, 256, 0, stream>>>(Wr, WrT);
            phi_kernel<<<(N + NPB - 1) / NPB, 256, 0, stream>>>(sf, W1, b1, W2, b2, phi, N);
            edge_kernel<<<(E + 3) / 4, 256, 0, stream>>>(idx_i, idx_j, rel_dir, rdc, rbf,
                                                         vf, WrT, br, phi, out_s, out_v, E);
        } else {
            edge_fused_kernel<<<(E + 3) / 4, 256, 0, stream>>>(idx_i, idx_j, rel_dir, rdc, rbf,
                                                               sf, vf, W1, b1, W2, b2, Wr, br,
                                                               out_s, out_v, E);
        }
    }
}

// Round 4
// 387.737 us; speedup vs baseline: 4.7031x; 1.2746x over previous
//
#include <hip/hip_runtime.h>
#include <hip/hip_fp16.h>

#define F 128
#define F3 384
#define NRBF 20
#define NPB 16   // nodes per block in phi kernel

typedef unsigned int u32;

// ---------------- transpose Wr [384][20] -> WrT [20][384] ----------------
__global__ void transpose_wr(const float* __restrict__ Wr, float* __restrict__ WrT) {
    int idx = blockIdx.x * blockDim.x + threadIdx.x;
    if (idx < F3 * NRBF) {
        int f = idx / NRBF, r = idx % NRBF;
        WrT[r * F3 + f] = Wr[idx];
    }
}

// ---------------- init d_out with inputs (fallback paths only) ----------------
__global__ void init_out(const float* __restrict__ sf, const float* __restrict__ vf,
                         float* __restrict__ out, int n_scalar, int n_total) {
    int i = blockIdx.x * blockDim.x + threadIdx.x;
    int n4 = n_total >> 2;
    if (i < n4) {
        float4 v;
        int base = i << 2;
        if (base < n_scalar) v = ((const float4*)sf)[i];
        else                 v = ((const float4*)vf)[i - (n_scalar >> 2)];
        ((float4*)out)[i] = v;
    }
}

// ---------------- per-node MLP phi = W2 @ silu(W1 @ x + b1) + b2 ----------------
// HALF_OUT=1: write fp16 phi in lane-permuted layout phi_p[node][(f&63)*6 + (f>>6)]
template<int HALF_OUT>
__launch_bounds__(256)
__global__ void phi_kernel(const float* __restrict__ sf,
                           const float* __restrict__ W1, const float* __restrict__ b1,
                           const float* __restrict__ W2, const float* __restrict__ b2,
                           float* __restrict__ phi, __half* __restrict__ phi_p, int n_nodes) {
    __shared__ float xs[NPB][F];
    __shared__ float hs[NPB][F];
    int tid = threadIdx.x;
    int nb = blockIdx.x * NPB;

    for (int t = tid; t < NPB * F / 4; t += 256) {
        int n  = t / (F / 4);
        int k4 = t % (F / 4);
        float4 v = make_float4(0.f, 0.f, 0.f, 0.f);
        if (nb + n < n_nodes) v = ((const float4*)(sf + (size_t)(nb + n) * F))[k4];
        ((float4*)&xs[n][0])[k4] = v;
    }
    __syncthreads();

    {
        int f = tid & (F - 1);
        int half_ = tid >> 7;
        float acc[8];
#pragma unroll
        for (int nn = 0; nn < 8; nn++) acc[nn] = 0.f;
        const float* w1row = W1 + (size_t)f * F;
        for (int k = 0; k < F; k++) {
            float w = w1row[k];
#pragma unroll
            for (int nn = 0; nn < 8; nn++)
                acc[nn] += xs[half_ * 8 + nn][k] * w;
        }
        float b = b1[f];
#pragma unroll
        for (int nn = 0; nn < 8; nn++) {
            float v = acc[nn] + b;
            hs[half_ * 8 + nn][f] = v / (1.f + __expf(-v));
        }
    }
    __syncthreads();

    for (int f = tid; f < F3; f += 256) {
        float acc[NPB];
#pragma unroll
        for (int n = 0; n < NPB; n++) acc[n] = 0.f;
        const float* w2row = W2 + (size_t)f * F;
        for (int k = 0; k < F; k++) {
            float w = w2row[k];
#pragma unroll
            for (int n = 0; n < NPB; n++)
                acc[n] += hs[n][k] * w;
        }
        float b = b2[f];
        for (int n = 0; n < NPB; n++) {
            if (nb + n < n_nodes) {
                float val = acc[n] + b;
                if (HALF_OUT)
                    phi_p[(size_t)(nb + n) * F3 + (f & 63) * 6 + (f >> 6)] = __float2half(val);
                else
                    phi[(size_t)(nb + n) * F3 + f] = val;
            }
        }
    }
}

// ---------------- vf -> fp16 lane-permuted copy: vfp[node][lane*6+{0..5}] ----------------
__global__ void vf_permute(const float* __restrict__ vf, __half* __restrict__ vfp, int n_nodes) {
    int t = blockIdx.x * blockDim.x + threadIdx.x;
    int node = t >> 6, lane = t & 63;
    if (node >= n_nodes) return;
    const float* v = vf + (size_t)node * F3;
    float a0 = v[lane * 3 + 0], a1 = v[lane * 3 + 1], a2 = v[lane * 3 + 2];
    float b0 = v[(lane + 64) * 3 + 0], b1 = v[(lane + 64) * 3 + 1], b2 = v[(lane + 64) * 3 + 2];
    __half2 h0, h1, h2;
    h0.x = __float2half(a0); h0.y = __float2half(a1);
    h1.x = __float2half(a2); h1.y = __float2half(b0);
    h2.x = __float2half(b1); h2.y = __float2half(b2);
    u32* o = (u32*)(vfp + (size_t)node * F3) + lane * 3;
    o[0] = *(u32*)&h0; o[1] = *(u32*)&h1; o[2] = *(u32*)&h2;
}

// ---------------- CSR build ----------------
__global__ void zero_counts(int* __restrict__ counts, int n) {
    int i = blockIdx.x * blockDim.x + threadIdx.x;
    if (i < n) counts[i] = 0;
}

__global__ void hist_kernel(const int* __restrict__ idx_i, int* __restrict__ counts, int n_edges) {
    int e = blockIdx.x * blockDim.x + threadIdx.x;
    if (e < n_edges) atomicAdd(&counts[idx_i[e]], 1);
}

__launch_bounds__(1024)
__global__ void scan_kernel(const int* __restrict__ counts, int* __restrict__ row_start,
                            int* __restrict__ cursor, int n) {
    __shared__ int partial[1024];
    int t = threadIdx.x;
    int C = (n + 1023) / 1024;
    int beg = t * C;
    int end = min(beg + C, n);
    int sum = 0;
    for (int i = beg; i < end; i++) sum += counts[i];
    partial[t] = sum;
    __syncthreads();
    for (int off = 1; off < 1024; off <<= 1) {
        int v = (t >= off) ? partial[t - off] : 0;
        __syncthreads();
        partial[t] += v;
        __syncthreads();
    }
    int base = (t == 0) ? 0 : partial[t - 1];
    for (int i = beg; i < end; i++) {
        row_start[i] = base;
        cursor[i] = base;
        base += counts[i];
    }
    if (t == 1023) row_start[n] = partial[1023];
}

__global__ void scatter_kernel(const int* __restrict__ idx_i, int* __restrict__ cursor,
                               int* __restrict__ edge_order, int n_edges) {
    int e = blockIdx.x * blockDim.x + threadIdx.x;
    if (e < n_edges) {
        int p = atomicAdd(&cursor[idx_i[e]], 1);
        edge_order[p] = e;
    }
}

// ---------------- gather v2: parallel metadata + pipelined fp16 gathers ----------------
struct EBuf { u32 p0, p1, p2, v0, v1, v2; float4 r0, r1, r2, r3, r4; };

__device__ __forceinline__ float2 uph(u32 u) {
    __half2 h = *(__half2*)&u;
    return make_float2(__half2float(h.x), __half2float(h.y));
}

__launch_bounds__(256)
__global__ void gather2_kernel(const int* __restrict__ idx_j,
                               const float* __restrict__ rel_dir, const float* __restrict__ rdc,
                               const float* __restrict__ rbf,
                               const float* __restrict__ sf, const float* __restrict__ vf,
                               const __half* __restrict__ phi_p, const __half* __restrict__ vfp,
                               const float* __restrict__ WrT, const float* __restrict__ br,
                               const int* __restrict__ row_start, const int* __restrict__ edge_order,
                               float* __restrict__ out_s, float* __restrict__ out_v,
                               int n_nodes) {
    int lane = threadIdx.x & 63;
    int node = blockIdx.x * 4 + (threadIdx.x >> 6);
    if (node >= n_nodes) return;

    // hoist RBF weights for this lane's 6 features (coalesced, loop-invariant)
    float wr[6][NRBF];
#pragma unroll
    for (int r = 0; r < NRBF; r++) {
#pragma unroll
        for (int q = 0; q < 6; q++)
            wr[q][r] = WrT[r * F3 + lane + 64 * q];
    }
    float brv[6];
#pragma unroll
    for (int q = 0; q < 6; q++) brv[q] = br[lane + 64 * q];

    float acc_s0 = 0.f, acc_s1 = 0.f;
    float av00 = 0.f, av01 = 0.f, av02 = 0.f, av10 = 0.f, av11 = 0.f, av12 = 0.f;

    const u32* phi_u = (const u32*)phi_p;
    const u32* vfp_u = (const u32*)vfp;
    const float4* rbf4 = (const float4*)rbf;

    int beg = row_start[node];
    int end = row_start[node + 1];

    for (int cb = beg; cb < end; cb += 64) {
        int cnt = min(64, end - cb);

        // phase 1: parallel metadata load (lane l -> edge cb+l)
        int ev = 0, jv = 0;
        float rdv = 0.f, dxv = 0.f, dyv = 0.f, dzv = 0.f;
        if (lane < cnt) {
            int e = edge_order[cb + lane];
            ev = e;
            jv = idx_j[e];
            rdv = rdc[e];
            dxv = rel_dir[e * 3 + 0];
            dyv = rel_dir[e * 3 + 1];
            dzv = rel_dir[e * 3 + 2];
        }

        auto issue = [&](EBuf& b, int k) {
            int e = __shfl(ev, k, 64);
            int j = __shfl(jv, k, 64);
            const u32* pp = phi_u + (size_t)j * (F3 / 2) + lane * 3;
            b.p0 = pp[0]; b.p1 = pp[1]; b.p2 = pp[2];
            const u32* vp = vfp_u + (size_t)j * (F3 / 2) + lane * 3;
            b.v0 = vp[0]; b.v1 = vp[1]; b.v2 = vp[2];
            const float4* rp = rbf4 + (size_t)e * (NRBF / 4);
            b.r0 = rp[0]; b.r1 = rp[1]; b.r2 = rp[2]; b.r3 = rp[3]; b.r4 = rp[4];
        };

        auto compute = [&](const EBuf& b, int k) {
            float rd = __shfl(rdv, k, 64);
            float dx = __shfl(dxv, k, 64);
            float dy = __shfl(dyv, k, 64);
            float dz = __shfl(dzv, k, 64);
            float rb[NRBF] = { b.r0.x, b.r0.y, b.r0.z, b.r0.w,
                               b.r1.x, b.r1.y, b.r1.z, b.r1.w,
                               b.r2.x, b.r2.y, b.r2.z, b.r2.w,
                               b.r3.x, b.r3.y, b.r3.z, b.r3.w,
                               b.r4.x, b.r4.y, b.r4.z, b.r4.w };
            float2 p01 = uph(b.p0), p23 = uph(b.p1), p45 = uph(b.p2);
            float pj[6] = { p01.x, p01.y, p23.x, p23.y, p45.x, p45.y };
            float pw[6];
#pragma unroll
            for (int q = 0; q < 6; q++) {
                float a = brv[q];
#pragma unroll
                for (int r = 0; r < NRBF; r++) a += rb[r] * wr[q][r];
                pw[q] = a * rd * pj[q];
            }
            acc_s0 += pw[2];
            acc_s1 += pw[3];
            float2 va = uph(b.v0), vb = uph(b.v1), vc = uph(b.v2);
            av00 += va.x * pw[0] + pw[4] * dx;
            av01 += va.y * pw[0] + pw[4] * dy;
            av02 += vb.x * pw[0] + pw[4] * dz;
            av10 += vb.y * pw[1] + pw[5] * dx;
            av11 += vc.x * pw[1] + pw[5] * dy;
            av12 += vc.y * pw[1] + pw[5] * dz;
        };

        // depth-2 software pipeline, named buffers (no runtime indexing)
        EBuf A, B;
        issue(A, 0);
        int k = 0;
        while (k + 2 <= cnt) {
            issue(B, k + 1);
            compute(A, k);
            if (k + 2 < cnt) issue(A, k + 2);
            compute(B, k + 1);
            k += 2;
        }
        if (k < cnt) compute(A, k);
    }

    // single non-atomic write: out = input + residual
    const float* sfi = sf + (size_t)node * F;
    float* osi = out_s + (size_t)node * F;
    osi[lane]      = sfi[lane]      + acc_s0;
    osi[lane + 64] = sfi[lane + 64] + acc_s1;

    const float* vfi = vf + (size_t)node * F3;
    float* ovi = out_v + (size_t)node * F3;
    ovi[lane * 3 + 0] = vfi[lane * 3 + 0] + av00;
    ovi[lane * 3 + 1] = vfi[lane * 3 + 1] + av01;
    ovi[lane * 3 + 2] = vfi[lane * 3 + 2] + av02;
    ovi[(lane + 64) * 3 + 0] = vfi[(lane + 64) * 3 + 0] + av10;
    ovi[(lane + 64) * 3 + 1] = vfi[(lane + 64) * 3 + 1] + av11;
    ovi[(lane + 64) * 3 + 2] = vfi[(lane + 64) * 3 + 2] + av12;
}

// ---------------- gather v1 (fp32, fallback) ----------------
__launch_bounds__(256)
__global__ void gather_kernel(const int* __restrict__ idx_j,
                              const float* __restrict__ rel_dir, const float* __restrict__ rdc,
                              const float* __restrict__ rbf,
                              const float* __restrict__ sf, const float* __restrict__ vf,
                              const float* __restrict__ WrT, const float* __restrict__ br,
                              const float* __restrict__ phi,
                              const int* __restrict__ row_start, const int* __restrict__ edge_order,
                              float* __restrict__ out_s, float* __restrict__ out_v,
                              int n_nodes) {
    int lane = threadIdx.x & 63;
    int node = blockIdx.x * 4 + (threadIdx.x >> 6);
    if (node >= n_nodes) return;

    float wr[6][NRBF];
#pragma unroll
    for (int r = 0; r < NRBF; r++)
#pragma unroll
        for (int q = 0; q < 6; q++)
            wr[q][r] = WrT[r * F3 + lane + 64 * q];
    float brv[6];
#pragma unroll
    for (int q = 0; q < 6; q++) brv[q] = br[lane + 64 * q];

    float acc_s0 = 0.f, acc_s1 = 0.f;
    float av[2][3];
#pragma unroll
    for (int h = 0; h < 2; h++)
#pragma unroll
        for (int c = 0; c < 3; c++) av[h][c] = 0.f;

    int beg = row_start[node];
    int end = row_start[node + 1];

    for (int k = beg; k < end; k++) {
        int e = edge_order[k];
        e = __builtin_amdgcn_readfirstlane(e);
        int j = idx_j[e];
        j = __builtin_amdgcn_readfirstlane(j);
        float rd = rdc[e];
        float d0 = rel_dir[e * 3 + 0], d1 = rel_dir[e * 3 + 1], d2 = rel_dir[e * 3 + 2];

        float rb[NRBF];
#pragma unroll
        for (int r = 0; r < NRBF; r++) rb[r] = rbf[(size_t)e * NRBF + r];

        const float* pj = phi + (size_t)j * F3;
        float pjv[6];
#pragma unroll
        for (int q = 0; q < 6; q++) pjv[q] = pj[lane + 64 * q];

        float pw[6];
#pragma unroll
        for (int q = 0; q < 6; q++) {
            float a = brv[q];
#pragma unroll
            for (int r = 0; r < NRBF; r++) a += rb[r] * wr[q][r];
            pw[q] = a * rd * pjv[q];
        }

        acc_s0 += pw[2];
        acc_s1 += pw[3];

        const float* vfj = vf + (size_t)j * F * 3;
#pragma unroll
        for (int h = 0; h < 2; h++) {
            int f = lane + 64 * h;
            float vv = pw[h];
            float vs = pw[4 + h];
            av[h][0] += vfj[f * 3 + 0] * vv + vs * d0;
            av[h][1] += vfj[f * 3 + 1] * vv + vs * d1;
            av[h][2] += vfj[f * 3 + 2] * vv + vs * d2;
        }
    }

    const float* sfi = sf + (size_t)node * F;
    float* osi = out_s + (size_t)node * F;
    osi[lane]      = sfi[lane]      + acc_s0;
    osi[lane + 64] = sfi[lane + 64] + acc_s1;

    const float* vfi = vf + (size_t)node * F * 3;
    float* ovi = out_v + (size_t)node * F * 3;
#pragma unroll
    for (int h = 0; h < 2; h++) {
        int f = lane + 64 * h;
#pragma unroll
        for (int c = 0; c < 3; c++)
            ovi[f * 3 + c] = vfi[f * 3 + c] + av[h][c];
    }
}

// ---------------- fallback: per-edge atomics ----------------
__launch_bounds__(256)
__global__ void edge_kernel(const int* __restrict__ idx_i, const int* __restrict__ idx_j,
                            const float* __restrict__ rel_dir, const float* __restrict__ rdc,
                            const float* __restrict__ rbf,
                            const float* __restrict__ vf,
                            const float* __restrict__ WrT, const float* __restrict__ br,
                            const float* __restrict__ phi,
                            float* __restrict__ out_s, float* __restrict__ out_v,
                            int n_edges) {
    int lane = threadIdx.x & 63;
    int e = (int)((blockIdx.x * (unsigned)blockDim.x + threadIdx.x) >> 6);
    if (e >= n_edges) return;

    int i = idx_i[e], j = idx_j[e];
    float rd = rdc[e];
    float d0 = rel_dir[e * 3 + 0], d1 = rel_dir[e * 3 + 1], d2 = rel_dir[e * 3 + 2];

    float rb[NRBF];
#pragma unroll
    for (int r = 0; r < NRBF; r++) rb[r] = rbf[(size_t)e * NRBF + r];

    const float* pj = phi + (size_t)j * F3;
    float pw[6];
#pragma unroll
    for (int q = 0; q < 6; q++) {
        int f = lane + 64 * q;
        float acc = br[f];
#pragma unroll
        for (int r = 0; r < NRBF; r++)
            acc += rb[r] * WrT[r * F3 + f];
        pw[q] = acc * rd * pj[f];
    }

    atomicAdd(&out_s[(size_t)i * F + lane],       pw[2]);
    atomicAdd(&out_s[(size_t)i * F + lane + 64],  pw[3]);

    const float* vfj = vf + (size_t)j * F * 3;
    float* ovi = out_v + (size_t)i * F * 3;
#pragma unroll
    for (int h = 0; h < 2; h++) {
        int f = lane + 64 * h;
        float vv = pw[h];
        float vs = pw[4 + h];
        atomicAdd(&ovi[f * 3 + 0], vfj[f * 3 + 0] * vv + vs * d0);
        atomicAdd(&ovi[f * 3 + 1], vfj[f * 3 + 1] * vv + vs * d1);
        atomicAdd(&ovi[f * 3 + 2], vfj[f * 3 + 2] * vv + vs * d2);
    }
}

extern "C" void kernel_launch(void* const* d_in, const int* in_sizes, int n_in,
                              void* d_out, int out_size, void* d_ws, size_t ws_size,
                              hipStream_t stream) {
    const int*   idx_i   = (const int*)d_in[0];
    const int*   idx_j   = (const int*)d_in[1];
    const float* rel_dir = (const float*)d_in[2];
    const float* rdc     = (const float*)d_in[3];
    const float* rbf     = (const float*)d_in[4];
    const float* sf      = (const float*)d_in[5];
    const float* vf      = (const float*)d_in[6];
    const float* W1      = (const float*)d_in[7];
    const float* b1      = (const float*)d_in[8];
    const float* W2      = (const float*)d_in[9];
    const float* b2      = (const float*)d_in[10];
    const float* Wr      = (const float*)d_in[11];
    const float* br      = (const float*)d_in[12];

    int E = in_sizes[0];
    int N = in_sizes[5] / F;

    float* out_s = (float*)d_out;
    float* out_v = out_s + (size_t)N * F;

    // ---- layout for new (fp16) path ----
    size_t off = 0;
    auto slab = [&](size_t bytes) { size_t o = off; off = (off + bytes + 255) & ~(size_t)255; return o; };
    size_t o_wrt  = slab((size_t)F3 * NRBF * sizeof(float));
    size_t o_phip = slab((size_t)N * F3 * sizeof(__half));
    size_t o_vfp  = slab((size_t)N * F3 * sizeof(__half));
    size_t o_cnt  = slab((size_t)N * sizeof(int));
    size_t o_row  = slab((size_t)(N + 1) * sizeof(int));
    size_t o_cur  = slab((size_t)N * sizeof(int));
    size_t o_ord  = slab((size_t)E * sizeof(int));
    size_t need_v2 = off;

    // ---- layout for fp32 fallback path ----
    size_t off2 = 0;
    auto slab2 = [&](size_t bytes) { size_t o = off2; off2 = (off2 + bytes + 255) & ~(size_t)255; return o; };
    size_t f_wrt = slab2((size_t)F3 * NRBF * sizeof(float));
    size_t f_phi = slab2((size_t)N * F3 * sizeof(float));
    size_t need_phi = off2;
    size_t f_cnt = slab2((size_t)N * sizeof(int));
    size_t f_row = slab2((size_t)(N + 1) * sizeof(int));
    size_t f_cur = slab2((size_t)N * sizeof(int));
    size_t f_ord = slab2((size_t)E * sizeof(int));
    size_t need_v1 = off2;

    if (ws_size >= need_v2) {
        float*  WrT       = (float*)((char*)d_ws + o_wrt);
        __half* phi_p     = (__half*)((char*)d_ws + o_phip);
        __half* vfp       = (__half*)((char*)d_ws + o_vfp);
        int*    counts    = (int*)((char*)d_ws + o_cnt);
        int*    row_start = (int*)((char*)d_ws + o_row);
        int*    cursor    = (int*)((char*)d_ws + o_cur);
        int*    edge_ord  = (int*)((char*)d_ws + o_ord);

        transpose_wr<<<(F3 * NRBF + 255) / 256, 256, 0, stream>>>(Wr, WrT);
        phi_kernel<1><<<(N + NPB - 1) / NPB, 256, 0, stream>>>(sf, W1, b1, W2, b2, nullptr, phi_p, N);
        vf_permute<<<(N * 64 + 255) / 256, 256, 0, stream>>>(vf, vfp, N);
        zero_counts<<<(N + 255) / 256, 256, 0, stream>>>(counts, N);
        hist_kernel<<<(E + 255) / 256, 256, 0, stream>>>(idx_i, counts, E);
        scan_kernel<<<1, 1024, 0, stream>>>(counts, row_start, cursor, N);
        scatter_kernel<<<(E + 255) / 256, 256, 0, stream>>>(idx_i, cursor, edge_ord, E);
        gather2_kernel<<<(N + 3) / 4, 256, 0, stream>>>(idx_j, rel_dir, rdc, rbf, sf, vf,
                                                        phi_p, vfp, WrT, br,
                                                        row_start, edge_ord, out_s, out_v, N);
    } else if (ws_size >= need_v1) {
        float* WrT       = (float*)((char*)d_ws + f_wrt);
        float* phi       = (float*)((char*)d_ws + f_phi);
        int*   counts    = (int*)((char*)d_ws + f_cnt);
        int*   row_start = (int*)((char*)d_ws + f_row);
        int*   cursor    = (int*)((char*)d_ws + f_cur);
        int*   edge_ord  = (int*)((char*)d_ws + f_ord);

        transpose_wr<<<(F3 * NRBF + 255) / 256, 256, 0, stream>>>(Wr, WrT);
        phi_kernel<0><<<(N + NPB - 1) / NPB, 256, 0, stream>>>(sf, W1, b1, W2, b2, phi, nullptr, N);
        zero_counts<<<(N + 255) / 256, 256, 0, stream>>>(counts, N);
        hist_kernel<<<(E + 255) / 256, 256, 0, stream>>>(idx_i, counts, E);
        scan_kernel<<<1, 1024, 0, stream>>>(counts, row_start, cursor, N);
        scatter_kernel<<<(E + 255) / 256, 256, 0, stream>>>(idx_i, cursor, edge_ord, E);
        gather_kernel<<<(N + 3) / 4, 256, 0, stream>>>(idx_j, rel_dir, rdc, rbf, sf, vf,
                                                       WrT, br, phi, row_start, edge_ord,
                                                       out_s, out_v, N);
    } else {
        // minimal ws: atomic path with fp32 phi
        int n_scalar = N * F;
        int n_total  = N * F * 4;
        int n4 = n_total / 4;
        init_out<<<(n4 + 255) / 256, 256, 0, stream>>>(sf, vf, (float*)d_out, n_scalar, n_total);
        float* WrT = (float*)((char*)d_ws + f_wrt);
        float* phi = (float*)((char*)d_ws + f_phi);
        transpose_wr<<<(F3 * NRBF + 255) / 256, 256, 0, stream>>>(Wr, WrT);
        phi_kernel<0><<<(N + NPB - 1) / NPB, 256, 0, stream>>>(sf, W1, b1, W2, b2, phi, nullptr, N);
        edge_kernel<<<(E + 3) / 4, 256, 0, stream>>>(idx_i, idx_j, rel_dir, rdc, rbf,
                                                     vf, WrT, br, phi, out_s, out_v, E);
    }
}

// Round 5
// 328.893 us; speedup vs baseline: 5.5445x; 1.1789x over previous
//
#include <hip/hip_runtime.h>
#include <hip/hip_fp16.h>

#define F 128
#define F3 384
#define NRBF 20
#define NPB 16

typedef unsigned int u32;

__device__ __forceinline__ float2 uph(u32 u) {
    __half2 h = *(__half2*)&u;
    return __half22float2(h);
}
__device__ __forceinline__ u32 pkh(float a, float b) {
    __half2 h = __floats2half2_rn(a, b);
    return *(u32*)&h;
}

// ---------------- shared MLP body: phi = W2 @ silu(W1 @ x + b1) + b2 ----------------
// HALF_OUT=1: write fp16 into gbuf slots [node][(f&63)*12 + ((f>>6)&1)*6 + (f>>7)]
template<int HALF_OUT>
__device__ __forceinline__ void phi_body(const float* __restrict__ sf,
                                         const float* __restrict__ W1, const float* __restrict__ b1,
                                         const float* __restrict__ W2, const float* __restrict__ b2,
                                         float* __restrict__ phi, __half* __restrict__ gbufh,
                                         int n_nodes, int nb, int tid,
                                         float (*xs)[F], float (*hs)[F]) {
    for (int t = tid; t < NPB * F / 4; t += 256) {
        int n  = t / (F / 4);
        int k4 = t % (F / 4);
        float4 v = make_float4(0.f, 0.f, 0.f, 0.f);
        if (nb + n < n_nodes) v = ((const float4*)(sf + (size_t)(nb + n) * F))[k4];
        ((float4*)&xs[n][0])[k4] = v;
    }
    __syncthreads();

    {
        int f = tid & (F - 1);
        int half_ = tid >> 7;
        float acc[8];
#pragma unroll
        for (int nn = 0; nn < 8; nn++) acc[nn] = 0.f;
        const float* w1row = W1 + (size_t)f * F;
        for (int k = 0; k < F; k++) {
            float w = w1row[k];
#pragma unroll
            for (int nn = 0; nn < 8; nn++)
                acc[nn] += xs[half_ * 8 + nn][k] * w;
        }
        float b = b1[f];
#pragma unroll
        for (int nn = 0; nn < 8; nn++) {
            float v = acc[nn] + b;
            hs[half_ * 8 + nn][f] = v / (1.f + __expf(-v));
        }
    }
    __syncthreads();

    for (int f = tid; f < F3; f += 256) {
        float acc[NPB];
#pragma unroll
        for (int n = 0; n < NPB; n++) acc[n] = 0.f;
        const float* w2row = W2 + (size_t)f * F;
        for (int k = 0; k < F; k++) {
            float w = w2row[k];
#pragma unroll
            for (int n = 0; n < NPB; n++)
                acc[n] += hs[n][k] * w;
        }
        float b = b2[f];
        int slot = (f & 63) * 12 + ((f >> 6) & 1) * 6 + (f >> 7);
        for (int n = 0; n < NPB; n++) {
            if (nb + n < n_nodes) {
                float val = acc[n] + b;
                if (HALF_OUT) gbufh[(size_t)(nb + n) * 768 + slot] = __float2half(val);
                else          phi[(size_t)(nb + n) * F3 + f] = val;
            }
        }
    }
}

// ---------------- A: pack Wr -> half2 WrTh[10][384] + zero counts ----------------
__global__ void prep_kernel(const float* __restrict__ Wr, u32* __restrict__ WrTh,
                            int* __restrict__ counts, int n_nodes) {
    int t = blockIdx.x * blockDim.x + threadIdx.x;
    if (t < 10 * F3) {
        int rr = t / F3, f = t % F3;
        WrTh[rr * F3 + f] = pkh(Wr[f * NRBF + 2 * rr], Wr[f * NRBF + 2 * rr + 1]);
    }
    int z = t - 10 * F3;
    if (z >= 0 && z < n_nodes) counts[z] = 0;
}

// ---------------- B: fused phi(half) + hist + vf-permute ----------------
__launch_bounds__(256)
__global__ void fusedB_kernel(const float* __restrict__ sf,
                              const float* __restrict__ W1, const float* __restrict__ b1,
                              const float* __restrict__ W2, const float* __restrict__ b2,
                              const int* __restrict__ idx_i, int* __restrict__ counts,
                              const float* __restrict__ vf, __half* __restrict__ gbufh,
                              int n_nodes, int n_edges, int PB, int HB) {
    __shared__ float xs[NPB][F];
    __shared__ float hs[NPB][F];
    int blk = blockIdx.x, tid = threadIdx.x;
    if (blk < PB) {
        phi_body<1>(sf, W1, b1, W2, b2, nullptr, gbufh, n_nodes, blk * NPB, tid, xs, hs);
    } else if (blk < PB + HB) {
        int e = (blk - PB) * 256 + tid;
        if (e < n_edges) atomicAdd(&counts[idx_i[e]], 1);
    } else {
        int idx = (blk - PB - HB) * 256 + tid;
        int node = idx >> 6, lane = idx & 63;
        if (node < n_nodes) {
            const float* v = vf + (size_t)node * F3;
            __half* g = gbufh + (size_t)node * 768 + lane * 12;
            g[3]  = __float2half(v[lane * 3 + 0]);
            g[4]  = __float2half(v[lane * 3 + 1]);
            g[5]  = __float2half(v[lane * 3 + 2]);
            g[9]  = __float2half(v[(lane + 64) * 3 + 0]);
            g[10] = __float2half(v[(lane + 64) * 3 + 1]);
            g[11] = __float2half(v[(lane + 64) * 3 + 2]);
        }
    }
}

// ---------------- C: LDS-staged single-block exclusive scan ----------------
#define SCAN_T 1024
#define SCAN_MAXN 25600
__launch_bounds__(SCAN_T)
__global__ void scan_lds_kernel(const int* __restrict__ counts, int* __restrict__ row_start,
                                int* __restrict__ cursor, int n) {
    __shared__ int sbuf[SCAN_MAXN];
    __shared__ int partial[SCAN_T];
    int t = threadIdx.x;
    for (int i = t; i < n; i += SCAN_T) sbuf[i] = counts[i];
    __syncthreads();
    int C = (n + SCAN_T - 1) / SCAN_T;
    int beg = t * C, end = min(beg + C, n);
    int sum = 0;
    for (int i = beg; i < end; i++) sum += sbuf[i];
    partial[t] = sum;
    __syncthreads();
    for (int off = 1; off < SCAN_T; off <<= 1) {
        int v = (t >= off) ? partial[t - off] : 0;
        __syncthreads();
        partial[t] += v;
        __syncthreads();
    }
    int base = (t == 0) ? 0 : partial[t - 1];
    for (int i = beg; i < end; i++) { int c = sbuf[i]; sbuf[i] = base; base += c; }
    __syncthreads();
    for (int i = t; i < n; i += SCAN_T) { int v = sbuf[i]; row_start[i] = v; cursor[i] = v; }
    if (t == SCAN_T - 1) row_start[n] = partial[SCAN_T - 1];
}

// fallback global scan (if N > SCAN_MAXN)
__launch_bounds__(1024)
__global__ void scan_kernel(const int* __restrict__ counts, int* __restrict__ row_start,
                            int* __restrict__ cursor, int n) {
    __shared__ int partial[1024];
    int t = threadIdx.x;
    int C = (n + 1023) / 1024;
    int beg = t * C, end = min(beg + C, n);
    int sum = 0;
    for (int i = beg; i < end; i++) sum += counts[i];
    partial[t] = sum;
    __syncthreads();
    for (int off = 1; off < 1024; off <<= 1) {
        int v = (t >= off) ? partial[t - off] : 0;
        __syncthreads();
        partial[t] += v;
        __syncthreads();
    }
    int base = (t == 0) ? 0 : partial[t - 1];
    for (int i = beg; i < end; i++) {
        int c = counts[i];
        row_start[i] = base; cursor[i] = base; base += c;
    }
    if (t == 1023) row_start[n] = partial[1023];
}

// ---------------- D: scatter ----------------
__global__ void scatter_kernel(const int* __restrict__ idx_i, int* __restrict__ cursor,
                               int* __restrict__ edge_order, int n_edges) {
    int e = blockIdx.x * blockDim.x + threadIdx.x;
    if (e < n_edges) {
        int p = atomicAdd(&cursor[idx_i[e]], 1);
        edge_order[p] = e;
    }
}

// ---------------- E: gather3 — 2 waves/node, fp16 packed math ----------------
__launch_bounds__(256)
__global__ void gather3_kernel(const int* __restrict__ idx_j,
                               const float* __restrict__ rel_dir, const float* __restrict__ rdc,
                               const float* __restrict__ rbf,
                               const float* __restrict__ sf, const float* __restrict__ vf,
                               const u32* __restrict__ WrTh, const float* __restrict__ br,
                               const u32* __restrict__ gbuf,
                               const int* __restrict__ row_start, const int* __restrict__ edge_order,
                               float* __restrict__ out_s, float* __restrict__ out_v,
                               int n_nodes) {
    int lane = threadIdx.x & 63;
    int w = (threadIdx.x >> 6) & 1;
    int node = blockIdx.x * 2 + (threadIdx.x >> 7);
    if (node >= n_nodes) return;

    int fb = lane + 64 * w;

    // fp16-packed RBF weight columns for this wave's 3 features: 30 VGPRs
    u32 wrpk[3][10];
    float brv[3];
#pragma unroll
    for (int k = 0; k < 3; k++) {
        brv[k] = br[fb + 128 * k];
#pragma unroll
        for (int rr = 0; rr < 10; rr++)
            wrpk[k][rr] = WrTh[rr * F3 + fb + 128 * k];
    }

    float acc_s = 0.f, av0 = 0.f, av1 = 0.f, av2 = 0.f;
    int beg = row_start[node];
    int end = row_start[node + 1];

    for (int cb = beg; cb < end; cb += 64) {
        int cnt = min(64, end - cb);

        // parallel per-chunk metadata: lane l owns edge cb+l
        int jv = 0; float rdv = 0.f, dxv = 0.f, dyv = 0.f, dzv = 0.f;
        u32 rbm[10];
#pragma unroll
        for (int rr = 0; rr < 10; rr++) rbm[rr] = 0;
        if (lane < cnt) {
            int e = edge_order[cb + lane];
            jv = idx_j[e];
            rdv = rdc[e];
            dxv = rel_dir[e * 3 + 0]; dyv = rel_dir[e * 3 + 1]; dzv = rel_dir[e * 3 + 2];
            const float4* rp = (const float4*)(rbf + (size_t)e * NRBF);
            float4 r0 = rp[0], r1 = rp[1], r2 = rp[2], r3 = rp[3], r4 = rp[4];
            rbm[0] = pkh(r0.x, r0.y); rbm[1] = pkh(r0.z, r0.w);
            rbm[2] = pkh(r1.x, r1.y); rbm[3] = pkh(r1.z, r1.w);
            rbm[4] = pkh(r2.x, r2.y); rbm[5] = pkh(r2.z, r2.w);
            rbm[6] = pkh(r3.x, r3.y); rbm[7] = pkh(r3.z, r3.w);
            rbm[8] = pkh(r4.x, r4.y); rbm[9] = pkh(r4.z, r4.w);
        }

        auto issue = [&](u32& g0, u32& g1, u32& g2, int k) {
            int j = __shfl(jv, k, 64);
            const u32* gp = gbuf + (size_t)j * 384 + lane * 6 + w * 3;
            g0 = gp[0]; g1 = gp[1]; g2 = gp[2];
        };
        auto compute = [&](u32 g0, u32 g1, u32 g2, int k) {
            float rd = __shfl(rdv, k, 64);
            float dx = __shfl(dxv, k, 64);
            float dy = __shfl(dyv, k, 64);
            float dz = __shfl(dzv, k, 64);
            __half2 wa0 = __floats2half2_rn(0.f, 0.f);
            __half2 wa1 = wa0, wa2 = wa0;
#pragma unroll
            for (int rr = 0; rr < 10; rr++) {
                int rbi = __shfl((int)rbm[rr], k, 64);
                __half2 rbh = *(__half2*)&rbi;
                wa0 = __hfma2(rbh, *(__half2*)&wrpk[0][rr], wa0);
                wa1 = __hfma2(rbh, *(__half2*)&wrpk[1][rr], wa1);
                wa2 = __hfma2(rbh, *(__half2*)&wrpk[2][rr], wa2);
            }
            float W0 = __half2float(wa0.x) + __half2float(wa0.y) + brv[0];
            float W1v = __half2float(wa1.x) + __half2float(wa1.y) + brv[1];
            float W2v = __half2float(wa2.x) + __half2float(wa2.y) + brv[2];
            float2 p01 = uph(g0);   // phi k0, k1
            float2 p2v0 = uph(g1);  // phi k2, vf c0
            float2 v12 = uph(g2);   // vf c1, c2
            float pw0 = W0 * rd * p01.x;
            float pw1 = W1v * rd * p01.y;
            float pw2 = W2v * rd * p2v0.x;
            acc_s += pw1;
            av0 += p2v0.y * pw0 + pw2 * dx;
            av1 += v12.x  * pw0 + pw2 * dy;
            av2 += v12.y  * pw0 + pw2 * dz;
        };

        // depth-2 software pipeline, named buffers
        u32 A0, A1, A2, B0, B1, B2;
        issue(A0, A1, A2, 0);
        int k = 0;
        while (k + 2 <= cnt) {
            issue(B0, B1, B2, k + 1);
            compute(A0, A1, A2, k);
            if (k + 2 < cnt) issue(A0, A1, A2, k + 2);
            compute(B0, B1, B2, k + 1);
            k += 2;
        }
        if (k < cnt) compute(A0, A1, A2, k);
    }

    // non-atomic residual write
    out_s[(size_t)node * F + fb] = sf[(size_t)node * F + fb] + acc_s;
    const float* vfi = vf + (size_t)node * F3 + fb * 3;
    float* ovi = out_v + (size_t)node * F3 + fb * 3;
    ovi[0] = vfi[0] + av0;
    ovi[1] = vfi[1] + av1;
    ovi[2] = vfi[2] + av2;
}

// ---------------- fallback path (tiny ws): f32 phi + atomic edge kernel ----------------
__global__ void transpose_wr(const float* __restrict__ Wr, float* __restrict__ WrT) {
    int idx = blockIdx.x * blockDim.x + threadIdx.x;
    if (idx < F3 * NRBF) {
        int f = idx / NRBF, r = idx % NRBF;
        WrT[r * F3 + f] = Wr[idx];
    }
}

__global__ void init_out(const float* __restrict__ sf, const float* __restrict__ vf,
                         float* __restrict__ out, int n_scalar, int n_total) {
    int i = blockIdx.x * blockDim.x + threadIdx.x;
    int n4 = n_total >> 2;
    if (i < n4) {
        float4 v;
        int base = i << 2;
        if (base < n_scalar) v = ((const float4*)sf)[i];
        else                 v = ((const float4*)vf)[i - (n_scalar >> 2)];
        ((float4*)out)[i] = v;
    }
}

__launch_bounds__(256)
__global__ void phi32_kernel(const float* __restrict__ sf,
                             const float* __restrict__ W1, const float* __restrict__ b1,
                             const float* __restrict__ W2, const float* __restrict__ b2,
                             float* __restrict__ phi, int n_nodes) {
    __shared__ float xs[NPB][F];
    __shared__ float hs[NPB][F];
    phi_body<0>(sf, W1, b1, W2, b2, phi, nullptr, n_nodes, blockIdx.x * NPB, threadIdx.x, xs, hs);
}

__launch_bounds__(256)
__global__ void edge_kernel(const int* __restrict__ idx_i, const int* __restrict__ idx_j,
                            const float* __restrict__ rel_dir, const float* __restrict__ rdc,
                            const float* __restrict__ rbf,
                            const float* __restrict__ vf,
                            const float* __restrict__ WrT, const float* __restrict__ br,
                            const float* __restrict__ phi,
                            float* __restrict__ out_s, float* __restrict__ out_v,
                            int n_edges) {
    int lane = threadIdx.x & 63;
    int e = (int)((blockIdx.x * (unsigned)blockDim.x + threadIdx.x) >> 6);
    if (e >= n_edges) return;

    int i = idx_i[e], j = idx_j[e];
    float rd = rdc[e];
    float d0 = rel_dir[e * 3 + 0], d1 = rel_dir[e * 3 + 1], d2 = rel_dir[e * 3 + 2];

    float rb[NRBF];
#pragma unroll
    for (int r = 0; r < NRBF; r++) rb[r] = rbf[(size_t)e * NRBF + r];

    const float* pj = phi + (size_t)j * F3;
    float pw[6];
#pragma unroll
    for (int q = 0; q < 6; q++) {
        int f = lane + 64 * q;
        float acc = br[f];
#pragma unroll
        for (int r = 0; r < NRBF; r++)
            acc += rb[r] * WrT[r * F3 + f];
        pw[q] = acc * rd * pj[f];
    }

    atomicAdd(&out_s[(size_t)i * F + lane],       pw[2]);
    atomicAdd(&out_s[(size_t)i * F + lane + 64],  pw[3]);

    const float* vfj = vf + (size_t)j * F * 3;
    float* ovi = out_v + (size_t)i * F * 3;
#pragma unroll
    for (int h = 0; h < 2; h++) {
        int f = lane + 64 * h;
        float vv = pw[h];
        float vs = pw[4 + h];
        atomicAdd(&ovi[f * 3 + 0], vfj[f * 3 + 0] * vv + vs * d0);
        atomicAdd(&ovi[f * 3 + 1], vfj[f * 3 + 1] * vv + vs * d1);
        atomicAdd(&ovi[f * 3 + 2], vfj[f * 3 + 2] * vv + vs * d2);
    }
}

extern "C" void kernel_launch(void* const* d_in, const int* in_sizes, int n_in,
                              void* d_out, int out_size, void* d_ws, size_t ws_size,
                              hipStream_t stream) {
    const int*   idx_i   = (const int*)d_in[0];
    const int*   idx_j   = (const int*)d_in[1];
    const float* rel_dir = (const float*)d_in[2];
    const float* rdc     = (const float*)d_in[3];
    const float* rbf     = (const float*)d_in[4];
    const float* sf      = (const float*)d_in[5];
    const float* vf      = (const float*)d_in[6];
    const float* W1      = (const float*)d_in[7];
    const float* b1      = (const float*)d_in[8];
    const float* W2      = (const float*)d_in[9];
    const float* b2      = (const float*)d_in[10];
    const float* Wr      = (const float*)d_in[11];
    const float* br      = (const float*)d_in[12];

    int E = in_sizes[0];
    int N = in_sizes[5] / F;

    float* out_s = (float*)d_out;
    float* out_v = out_s + (size_t)N * F;

    // ---- v3 workspace layout ----
    size_t off = 0;
    auto slab = [&](size_t bytes) { size_t o = off; off = (off + bytes + 255) & ~(size_t)255; return o; };
    size_t o_wrth = slab((size_t)10 * F3 * sizeof(u32));          // 15.4 KB
    size_t o_gbuf = slab((size_t)N * 768 * sizeof(__half));       // 38.4 MB
    size_t o_cnt  = slab((size_t)N * sizeof(int));                // counts (aliased as cursor)
    size_t o_row  = slab((size_t)(N + 1) * sizeof(int));
    size_t o_ord  = slab((size_t)E * sizeof(int));
    size_t need_v3 = off;

    if (ws_size >= need_v3) {
        u32*    WrTh      = (u32*)((char*)d_ws + o_wrth);
        __half* gbufh     = (__half*)((char*)d_ws + o_gbuf);
        u32*    gbuf      = (u32*)gbufh;
        int*    counts    = (int*)((char*)d_ws + o_cnt);
        int*    cursor    = counts;   // aliased: scan rewrites counts as cursor
        int*    row_start = (int*)((char*)d_ws + o_row);
        int*    edge_ord  = (int*)((char*)d_ws + o_ord);

        int prep_threads = 10 * F3 + N;
        prep_kernel<<<(prep_threads + 255) / 256, 256, 0, stream>>>(Wr, WrTh, counts, N);

        int PB = (N + NPB - 1) / NPB;
        int HB = (E + 255) / 256;
        int VB = (N + 3) / 4;
        fusedB_kernel<<<PB + HB + VB, 256, 0, stream>>>(sf, W1, b1, W2, b2, idx_i, counts,
                                                        vf, gbufh, N, E, PB, HB);
        if (N <= SCAN_MAXN)
            scan_lds_kernel<<<1, SCAN_T, 0, stream>>>(counts, row_start, cursor, N);
        else
            scan_kernel<<<1, 1024, 0, stream>>>(counts, row_start, cursor, N);
        scatter_kernel<<<(E + 255) / 256, 256, 0, stream>>>(idx_i, cursor, edge_ord, E);
        gather3_kernel<<<(N + 1) / 2, 256, 0, stream>>>(idx_j, rel_dir, rdc, rbf, sf, vf,
                                                        WrTh, br, gbuf, row_start, edge_ord,
                                                        out_s, out_v, N);
    } else {
        // minimal fallback: f32 phi + atomic scatter
        size_t off2 = 0;
        auto slab2 = [&](size_t bytes) { size_t o = off2; off2 = (off2 + bytes + 255) & ~(size_t)255; return o; };
        size_t f_wrt = slab2((size_t)F3 * NRBF * sizeof(float));
        size_t f_phi = slab2((size_t)N * F3 * sizeof(float));
        float* WrT = (float*)((char*)d_ws + f_wrt);
        float* phi = (float*)((char*)d_ws + f_phi);

        int n_scalar = N * F;
        int n_total  = N * F * 4;
        init_out<<<(n_total / 4 + 255) / 256, 256, 0, stream>>>(sf, vf, (float*)d_out, n_scalar, n_total);
        transpose_wr<<<(F3 * NRBF + 255) / 256, 256, 0, stream>>>(Wr, WrT);
        phi32_kernel<<<(N + NPB - 1) / NPB, 256, 0, stream>>>(sf, W1, b1, W2, b2, phi, N);
        edge_kernel<<<(E + 3) / 4, 256, 0, stream>>>(idx_i, idx_j, rel_dir, rdc, rbf,
                                                     vf, WrT, br, phi, out_s, out_v, E);
    }
}

// Round 6
// 288.152 us; speedup vs baseline: 6.3284x; 1.1414x over previous
//
#include <hip/hip_runtime.h>
#include <hip/hip_fp16.h>

#define F 128
#define F3 384
#define NRBF 20
#define NPB 16
#define CHUNK 64

typedef unsigned int u32;

__device__ __forceinline__ float2 uph(u32 u) {
    __half2 h = *(__half2*)&u;
    return __half22float2(h);
}
__device__ __forceinline__ u32 pkh(float a, float b) {
    __half2 h = __floats2half2_rn(a, b);
    return *(u32*)&h;
}

// ---------------- shared MLP body (float4 LDS reads) ----------------
// HALF_OUT=1: write fp16 into gbuf slots [node][(f&63)*12 + ((f>>6)&1)*6 + (f>>7)]
template<int HALF_OUT>
__device__ __forceinline__ void phi_body(const float* __restrict__ sf,
                                         const float* __restrict__ W1, const float* __restrict__ b1,
                                         const float* __restrict__ W2, const float* __restrict__ b2,
                                         float* __restrict__ phi, __half* __restrict__ gbufh,
                                         int n_nodes, int nb, int tid,
                                         float (*xs)[F], float (*hs)[F]) {
    for (int t = tid; t < NPB * F / 4; t += 256) {
        int n  = t / (F / 4);
        int k4 = t % (F / 4);
        float4 v = make_float4(0.f, 0.f, 0.f, 0.f);
        if (nb + n < n_nodes) v = ((const float4*)(sf + (size_t)(nb + n) * F))[k4];
        ((float4*)&xs[n][0])[k4] = v;
    }
    __syncthreads();

    {
        int f = tid & (F - 1);
        int half_ = tid >> 7;
        float acc[8];
#pragma unroll
        for (int nn = 0; nn < 8; nn++) acc[nn] = 0.f;
        const float4* w1row = (const float4*)(W1 + (size_t)f * F);
        for (int k4 = 0; k4 < F / 4; k4++) {
            float4 wv = w1row[k4];
#pragma unroll
            for (int nn = 0; nn < 8; nn++) {
                float4 x = *(const float4*)&xs[half_ * 8 + nn][k4 * 4];
                acc[nn] += x.x * wv.x + x.y * wv.y + x.z * wv.z + x.w * wv.w;
            }
        }
        float b = b1[f];
#pragma unroll
        for (int nn = 0; nn < 8; nn++) {
            float v = acc[nn] + b;
            hs[half_ * 8 + nn][f] = v / (1.f + __expf(-v));
        }
    }
    __syncthreads();

    for (int f = tid; f < F3; f += 256) {
        float acc[NPB];
#pragma unroll
        for (int n = 0; n < NPB; n++) acc[n] = 0.f;
        const float4* w2row = (const float4*)(W2 + (size_t)f * F);
        for (int k4 = 0; k4 < F / 4; k4++) {
            float4 wv = w2row[k4];
#pragma unroll
            for (int n = 0; n < NPB; n++) {
                float4 h = *(const float4*)&hs[n][k4 * 4];
                acc[n] += h.x * wv.x + h.y * wv.y + h.z * wv.z + h.w * wv.w;
            }
        }
        float b = b2[f];
        int slot = (f & 63) * 12 + ((f >> 6) & 1) * 6 + (f >> 7);
        for (int n = 0; n < NPB; n++) {
            if (nb + n < n_nodes) {
                float val = acc[n] + b;
                if (HALF_OUT) gbufh[(size_t)(nb + n) * 768 + slot] = __float2half(val);
                else          phi[(size_t)(nb + n) * F3 + f] = val;
            }
        }
    }
}

// ---------------- A: pack Wr -> half2 WrTh[10][384] + zero counts ----------------
__global__ void prep_kernel(const float* __restrict__ Wr, u32* __restrict__ WrTh,
                            int* __restrict__ counts, int n_nodes) {
    int t = blockIdx.x * blockDim.x + threadIdx.x;
    if (t < 10 * F3) {
        int rr = t / F3, f = t % F3;
        WrTh[rr * F3 + f] = pkh(Wr[f * NRBF + 2 * rr], Wr[f * NRBF + 2 * rr + 1]);
    }
    int z = t - 10 * F3;
    if (z >= 0 && z < n_nodes) counts[z] = 0;
}

// ---------------- B: fused phi(half) + hist + vf-permute ----------------
__launch_bounds__(256)
__global__ void fusedB_kernel(const float* __restrict__ sf,
                              const float* __restrict__ W1, const float* __restrict__ b1,
                              const float* __restrict__ W2, const float* __restrict__ b2,
                              const int* __restrict__ idx_i, int* __restrict__ counts,
                              const float* __restrict__ vf, __half* __restrict__ gbufh,
                              int n_nodes, int n_edges, int PB, int HB) {
    __shared__ float xs[NPB][F];
    __shared__ float hs[NPB][F];
    int blk = blockIdx.x, tid = threadIdx.x;
    if (blk < PB) {
        phi_body<1>(sf, W1, b1, W2, b2, nullptr, gbufh, n_nodes, blk * NPB, tid, xs, hs);
    } else if (blk < PB + HB) {
        int e = (blk - PB) * 256 + tid;
        if (e < n_edges) atomicAdd(&counts[idx_i[e]], 1);
    } else {
        int idx = (blk - PB - HB) * 256 + tid;
        int node = idx >> 6, lane = idx & 63;
        if (node < n_nodes) {
            const float* v = vf + (size_t)node * F3;
            __half* g = gbufh + (size_t)node * 768 + lane * 12;
            g[3]  = __float2half(v[lane * 3 + 0]);
            g[4]  = __float2half(v[lane * 3 + 1]);
            g[5]  = __float2half(v[lane * 3 + 2]);
            g[9]  = __float2half(v[(lane + 64) * 3 + 0]);
            g[10] = __float2half(v[(lane + 64) * 3 + 1]);
            g[11] = __float2half(v[(lane + 64) * 3 + 2]);
        }
    }
}

// ---------------- C: LDS-staged single-block exclusive scan ----------------
#define SCAN_T 1024
#define SCAN_MAXN 25600
__launch_bounds__(SCAN_T)
__global__ void scan_lds_kernel(const int* __restrict__ counts, int* __restrict__ row_start,
                                int* __restrict__ cursor, int n) {
    __shared__ int sbuf[SCAN_MAXN];
    __shared__ int partial[SCAN_T];
    int t = threadIdx.x;
    for (int i = t; i < n; i += SCAN_T) sbuf[i] = counts[i];
    __syncthreads();
    int C = (n + SCAN_T - 1) / SCAN_T;
    int beg = t * C, end = min(beg + C, n);
    int sum = 0;
    for (int i = beg; i < end; i++) sum += sbuf[i];
    partial[t] = sum;
    __syncthreads();
    for (int off = 1; off < SCAN_T; off <<= 1) {
        int v = (t >= off) ? partial[t - off] : 0;
        __syncthreads();
        partial[t] += v;
        __syncthreads();
    }
    int base = (t == 0) ? 0 : partial[t - 1];
    for (int i = beg; i < end; i++) { int c = sbuf[i]; sbuf[i] = base; base += c; }
    __syncthreads();
    for (int i = t; i < n; i += SCAN_T) { int v = sbuf[i]; row_start[i] = v; cursor[i] = v; }
    if (t == SCAN_T - 1) row_start[n] = partial[SCAN_T - 1];
}

__launch_bounds__(1024)
__global__ void scan_kernel(const int* __restrict__ counts, int* __restrict__ row_start,
                            int* __restrict__ cursor, int n) {
    __shared__ int partial[1024];
    int t = threadIdx.x;
    int C = (n + 1023) / 1024;
    int beg = t * C, end = min(beg + C, n);
    int sum = 0;
    for (int i = beg; i < end; i++) sum += counts[i];
    partial[t] = sum;
    __syncthreads();
    for (int off = 1; off < 1024; off <<= 1) {
        int v = (t >= off) ? partial[t - off] : 0;
        __syncthreads();
        partial[t] += v;
        __syncthreads();
    }
    int base = (t == 0) ? 0 : partial[t - 1];
    for (int i = beg; i < end; i++) {
        int c = counts[i];
        row_start[i] = base; cursor[i] = base; base += c;
    }
    if (t == 1023) row_start[n] = partial[1023];
}

// ---------------- D(v4): build sorted 64-B edge records ----------------
// layout (u32[16]): [0]=j [1]=rd [2]=dx [3]=dy [4]=dz [5+rr]=rbf half2 (rr=0..9) [15]=pad
__global__ void build_records(const int* __restrict__ idx_i, const int* __restrict__ idx_j,
                              const float* __restrict__ rel_dir, const float* __restrict__ rdc,
                              const float* __restrict__ rbf, int* __restrict__ cursor,
                              u32* __restrict__ recs, int n_edges) {
    int e = blockIdx.x * blockDim.x + threadIdx.x;
    if (e >= n_edges) return;
    int p = atomicAdd(&cursor[idx_i[e]], 1);
    u32 r[16];
    r[0] = (u32)idx_j[e];
    r[1] = __float_as_uint(rdc[e]);
    r[2] = __float_as_uint(rel_dir[e * 3 + 0]);
    r[3] = __float_as_uint(rel_dir[e * 3 + 1]);
    r[4] = __float_as_uint(rel_dir[e * 3 + 2]);
    const float* rb = rbf + (size_t)e * NRBF;
#pragma unroll
    for (int t = 0; t < 10; t++) r[5 + t] = pkh(rb[2 * t], rb[2 * t + 1]);
    r[15] = 0;
    float4* dst = (float4*)(recs + (size_t)p * 16);
    const float4* src = (const float4*)r;
    dst[0] = src[0]; dst[1] = src[1]; dst[2] = src[2]; dst[3] = src[3];
}

// ---------------- D(v3 fallback): scatter edge ids ----------------
__global__ void scatter_kernel(const int* __restrict__ idx_i, int* __restrict__ cursor,
                               int* __restrict__ edge_order, int n_edges) {
    int e = blockIdx.x * blockDim.x + threadIdx.x;
    if (e < n_edges) {
        int p = atomicAdd(&cursor[idx_i[e]], 1);
        edge_order[p] = e;
    }
}

// ---------------- E(v4): gather4 — records in LDS, uniform reads, depth-4 pipeline ----------------
__launch_bounds__(256)
__global__ void gather4_kernel(const float* __restrict__ sf, const float* __restrict__ vf,
                               const u32* __restrict__ WrTh, const float* __restrict__ br,
                               const u32* __restrict__ gbuf, const u32* __restrict__ recs,
                               const int* __restrict__ row_start,
                               float* __restrict__ out_s, float* __restrict__ out_v,
                               int n_nodes) {
    __shared__ u32 lsm[4][CHUNK * 16];   // 4 waves x 64 recs x 64 B = 16 KB
    int tid = threadIdx.x;
    int lane = tid & 63;
    int wvid = tid >> 6;
    int w = wvid & 1;
    int node = blockIdx.x * 2 + (wvid >> 1);
    if (node >= n_nodes) return;
    u32* lds = lsm[wvid];

    int fb = lane + 64 * w;
    u32 wrpk[3][10];
    float brv[3];
#pragma unroll
    for (int k = 0; k < 3; k++) {
        brv[k] = br[fb + 128 * k];
#pragma unroll
        for (int rr = 0; rr < 10; rr++)
            wrpk[k][rr] = WrTh[rr * F3 + fb + 128 * k];
    }

    float acc_s = 0.f, av0 = 0.f, av1 = 0.f, av2 = 0.f;
    int beg = row_start[node];
    int end = row_start[node + 1];

    for (int cb = beg; cb < end; cb += CHUNK) {
        int cnt = min(CHUNK, end - cb);

        // coalesced stage: cnt*4 float4s
        {
            const float4* src = (const float4*)(recs + (size_t)cb * 16);
            int nf4 = cnt * 4;
            for (int t = lane; t < nf4; t += 64)
                ((float4*)lds)[t] = src[t];
        }

        auto issueL = [&](u32& g0, u32& g1, u32& g2, int m) {
            if (m < cnt) {
                int j = (int)lds[m * 16];
                const u32* gp = gbuf + (size_t)j * 384 + lane * 6 + w * 3;
                g0 = gp[0]; g1 = gp[1]; g2 = gp[2];
            }
        };
        auto computeE = [&](u32 g0, u32 g1, u32 g2, int m) {
            const uint4* q = (const uint4*)(lds + m * 16);
            uint4 q0 = q[0], q1 = q[1], q2 = q[2], q3 = q[3];
            float rd = __uint_as_float(q0.y);
            float dx = __uint_as_float(q0.z);
            float dy = __uint_as_float(q0.w);
            float dz = __uint_as_float(q1.x);
            u32 rbu0 = q1.y, rbu1 = q1.z, rbu2 = q1.w;
            u32 rbu3 = q2.x, rbu4 = q2.y, rbu5 = q2.z, rbu6 = q2.w;
            u32 rbu7 = q3.x, rbu8 = q3.y, rbu9 = q3.z;
            __half2 z2 = __floats2half2_rn(0.f, 0.f);
            __half2 wa0 = z2, wa1 = z2, wa2 = z2;
            u32 rbu[10] = { rbu0, rbu1, rbu2, rbu3, rbu4, rbu5, rbu6, rbu7, rbu8, rbu9 };
#pragma unroll
            for (int rr = 0; rr < 10; rr++) {
                __half2 rbh = *(__half2*)&rbu[rr];
                wa0 = __hfma2(rbh, *(__half2*)&wrpk[0][rr], wa0);
                wa1 = __hfma2(rbh, *(__half2*)&wrpk[1][rr], wa1);
                wa2 = __hfma2(rbh, *(__half2*)&wrpk[2][rr], wa2);
            }
            float W0  = __half2float(wa0.x) + __half2float(wa0.y) + brv[0];
            float W1v = __half2float(wa1.x) + __half2float(wa1.y) + brv[1];
            float W2v = __half2float(wa2.x) + __half2float(wa2.y) + brv[2];
            float2 p01  = uph(g0);
            float2 p2v0 = uph(g1);
            float2 v12  = uph(g2);
            float pw0 = W0  * rd * p01.x;
            float pw1 = W1v * rd * p01.y;
            float pw2 = W2v * rd * p2v0.x;
            acc_s += pw1;
            av0 += p2v0.y * pw0 + pw2 * dx;
            av1 += v12.x  * pw0 + pw2 * dy;
            av2 += v12.y  * pw0 + pw2 * dz;
        };

        u32 A0, A1, A2, B0, B1, B2, C0, C1, C2, D0, D1, D2;
        issueL(A0, A1, A2, 0); issueL(B0, B1, B2, 1);
        issueL(C0, C1, C2, 2); issueL(D0, D1, D2, 3);
        int m = 0;
        while (true) {
            if (m >= cnt) break; computeE(A0, A1, A2, m); m++; issueL(A0, A1, A2, m + 3);
            if (m >= cnt) break; computeE(B0, B1, B2, m); m++; issueL(B0, B1, B2, m + 3);
            if (m >= cnt) break; computeE(C0, C1, C2, m); m++; issueL(C0, C1, C2, m + 3);
            if (m >= cnt) break; computeE(D0, D1, D2, m); m++; issueL(D0, D1, D2, m + 3);
        }
    }

    out_s[(size_t)node * F + fb] = sf[(size_t)node * F + fb] + acc_s;
    const float* vfi = vf + (size_t)node * F3 + fb * 3;
    float* ovi = out_v + (size_t)node * F3 + fb * 3;
    ovi[0] = vfi[0] + av0;
    ovi[1] = vfi[1] + av1;
    ovi[2] = vfi[2] + av2;
}

// ---------------- E(v3 fallback): gather3 (R5) ----------------
__launch_bounds__(256)
__global__ void gather3_kernel(const int* __restrict__ idx_j,
                               const float* __restrict__ rel_dir, const float* __restrict__ rdc,
                               const float* __restrict__ rbf,
                               const float* __restrict__ sf, const float* __restrict__ vf,
                               const u32* __restrict__ WrTh, const float* __restrict__ br,
                               const u32* __restrict__ gbuf,
                               const int* __restrict__ row_start, const int* __restrict__ edge_order,
                               float* __restrict__ out_s, float* __restrict__ out_v,
                               int n_nodes) {
    int lane = threadIdx.x & 63;
    int w = (threadIdx.x >> 6) & 1;
    int node = blockIdx.x * 2 + (threadIdx.x >> 7);
    if (node >= n_nodes) return;

    int fb = lane + 64 * w;
    u32 wrpk[3][10];
    float brv[3];
#pragma unroll
    for (int k = 0; k < 3; k++) {
        brv[k] = br[fb + 128 * k];
#pragma unroll
        for (int rr = 0; rr < 10; rr++)
            wrpk[k][rr] = WrTh[rr * F3 + fb + 128 * k];
    }

    float acc_s = 0.f, av0 = 0.f, av1 = 0.f, av2 = 0.f;
    int beg = row_start[node];
    int end = row_start[node + 1];

    for (int cb = beg; cb < end; cb += 64) {
        int cnt = min(64, end - cb);
        int jv = 0; float rdv = 0.f, dxv = 0.f, dyv = 0.f, dzv = 0.f;
        u32 rbm[10];
#pragma unroll
        for (int rr = 0; rr < 10; rr++) rbm[rr] = 0;
        if (lane < cnt) {
            int e = edge_order[cb + lane];
            jv = idx_j[e];
            rdv = rdc[e];
            dxv = rel_dir[e * 3 + 0]; dyv = rel_dir[e * 3 + 1]; dzv = rel_dir[e * 3 + 2];
            const float4* rp = (const float4*)(rbf + (size_t)e * NRBF);
            float4 r0 = rp[0], r1 = rp[1], r2 = rp[2], r3 = rp[3], r4 = rp[4];
            rbm[0] = pkh(r0.x, r0.y); rbm[1] = pkh(r0.z, r0.w);
            rbm[2] = pkh(r1.x, r1.y); rbm[3] = pkh(r1.z, r1.w);
            rbm[4] = pkh(r2.x, r2.y); rbm[5] = pkh(r2.z, r2.w);
            rbm[6] = pkh(r3.x, r3.y); rbm[7] = pkh(r3.z, r3.w);
            rbm[8] = pkh(r4.x, r4.y); rbm[9] = pkh(r4.z, r4.w);
        }
        auto issue = [&](u32& g0, u32& g1, u32& g2, int k) {
            int j = __shfl(jv, k, 64);
            const u32* gp = gbuf + (size_t)j * 384 + lane * 6 + w * 3;
            g0 = gp[0]; g1 = gp[1]; g2 = gp[2];
        };
        auto compute = [&](u32 g0, u32 g1, u32 g2, int k) {
            float rd = __shfl(rdv, k, 64);
            float dx = __shfl(dxv, k, 64);
            float dy = __shfl(dyv, k, 64);
            float dz = __shfl(dzv, k, 64);
            __half2 z2 = __floats2half2_rn(0.f, 0.f);
            __half2 wa0 = z2, wa1 = z2, wa2 = z2;
#pragma unroll
            for (int rr = 0; rr < 10; rr++) {
                int rbi = __shfl((int)rbm[rr], k, 64);
                __half2 rbh = *(__half2*)&rbi;
                wa0 = __hfma2(rbh, *(__half2*)&wrpk[0][rr], wa0);
                wa1 = __hfma2(rbh, *(__half2*)&wrpk[1][rr], wa1);
                wa2 = __hfma2(rbh, *(__half2*)&wrpk[2][rr], wa2);
            }
            float W0 = __half2float(wa0.x) + __half2float(wa0.y) + brv[0];
            float W1v = __half2float(wa1.x) + __half2float(wa1.y) + brv[1];
            float W2v = __half2float(wa2.x) + __half2float(wa2.y) + brv[2];
            float2 p01 = uph(g0);
            float2 p2v0 = uph(g1);
            float2 v12 = uph(g2);
            float pw0 = W0 * rd * p01.x;
            float pw1 = W1v * rd * p01.y;
            float pw2 = W2v * rd * p2v0.x;
            acc_s += pw1;
            av0 += p2v0.y * pw0 + pw2 * dx;
            av1 += v12.x  * pw0 + pw2 * dy;
            av2 += v12.y  * pw0 + pw2 * dz;
        };
        u32 A0, A1, A2, B0, B1, B2;
        issue(A0, A1, A2, 0);
        int k = 0;
        while (k + 2 <= cnt) {
            issue(B0, B1, B2, k + 1);
            compute(A0, A1, A2, k);
            if (k + 2 < cnt) issue(A0, A1, A2, k + 2);
            compute(B0, B1, B2, k + 1);
            k += 2;
        }
        if (k < cnt) compute(A0, A1, A2, k);
    }

    out_s[(size_t)node * F + fb] = sf[(size_t)node * F + fb] + acc_s;
    const float* vfi = vf + (size_t)node * F3 + fb * 3;
    float* ovi = out_v + (size_t)node * F3 + fb * 3;
    ovi[0] = vfi[0] + av0;
    ovi[1] = vfi[1] + av1;
    ovi[2] = vfi[2] + av2;
}

// ---------------- tiny-ws fallback ----------------
__global__ void transpose_wr(const float* __restrict__ Wr, float* __restrict__ WrT) {
    int idx = blockIdx.x * blockDim.x + threadIdx.x;
    if (idx < F3 * NRBF) {
        int f = idx / NRBF, r = idx % NRBF;
        WrT[r * F3 + f] = Wr[idx];
    }
}

__global__ void init_out(const float* __restrict__ sf, const float* __restrict__ vf,
                         float* __restrict__ out, int n_scalar, int n_total) {
    int i = blockIdx.x * blockDim.x + threadIdx.x;
    int n4 = n_total >> 2;
    if (i < n4) {
        float4 v;
        int base = i << 2;
        if (base < n_scalar) v = ((const float4*)sf)[i];
        else                 v = ((const float4*)vf)[i - (n_scalar >> 2)];
        ((float4*)out)[i] = v;
    }
}

__launch_bounds__(256)
__global__ void phi32_kernel(const float* __restrict__ sf,
                             const float* __restrict__ W1, const float* __restrict__ b1,
                             const float* __restrict__ W2, const float* __restrict__ b2,
                             float* __restrict__ phi, int n_nodes) {
    __shared__ float xs[NPB][F];
    __shared__ float hs[NPB][F];
    phi_body<0>(sf, W1, b1, W2, b2, phi, nullptr, n_nodes, blockIdx.x * NPB, threadIdx.x, xs, hs);
}

__launch_bounds__(256)
__global__ void edge_kernel(const int* __restrict__ idx_i, const int* __restrict__ idx_j,
                            const float* __restrict__ rel_dir, const float* __restrict__ rdc,
                            const float* __restrict__ rbf,
                            const float* __restrict__ vf,
                            const float* __restrict__ WrT, const float* __restrict__ br,
                            const float* __restrict__ phi,
                            float* __restrict__ out_s, float* __restrict__ out_v,
                            int n_edges) {
    int lane = threadIdx.x & 63;
    int e = (int)((blockIdx.x * (unsigned)blockDim.x + threadIdx.x) >> 6);
    if (e >= n_edges) return;

    int i = idx_i[e], j = idx_j[e];
    float rd = rdc[e];
    float d0 = rel_dir[e * 3 + 0], d1 = rel_dir[e * 3 + 1], d2 = rel_dir[e * 3 + 2];

    float rb[NRBF];
#pragma unroll
    for (int r = 0; r < NRBF; r++) rb[r] = rbf[(size_t)e * NRBF + r];

    const float* pj = phi + (size_t)j * F3;
    float pw[6];
#pragma unroll
    for (int q = 0; q < 6; q++) {
        int f = lane + 64 * q;
        float acc = br[f];
#pragma unroll
        for (int r = 0; r < NRBF; r++)
            acc += rb[r] * WrT[r * F3 + f];
        pw[q] = acc * rd * pj[f];
    }

    atomicAdd(&out_s[(size_t)i * F + lane],       pw[2]);
    atomicAdd(&out_s[(size_t)i * F + lane + 64],  pw[3]);

    const float* vfj = vf + (size_t)j * F * 3;
    float* ovi = out_v + (size_t)i * F * 3;
#pragma unroll
    for (int h = 0; h < 2; h++) {
        int f = lane + 64 * h;
        float vv = pw[h];
        float vs = pw[4 + h];
        atomicAdd(&ovi[f * 3 + 0], vfj[f * 3 + 0] * vv + vs * d0);
        atomicAdd(&ovi[f * 3 + 1], vfj[f * 3 + 1] * vv + vs * d1);
        atomicAdd(&ovi[f * 3 + 2], vfj[f * 3 + 2] * vv + vs * d2);
    }
}

extern "C" void kernel_launch(void* const* d_in, const int* in_sizes, int n_in,
                              void* d_out, int out_size, void* d_ws, size_t ws_size,
                              hipStream_t stream) {
    const int*   idx_i   = (const int*)d_in[0];
    const int*   idx_j   = (const int*)d_in[1];
    const float* rel_dir = (const float*)d_in[2];
    const float* rdc     = (const float*)d_in[3];
    const float* rbf     = (const float*)d_in[4];
    const float* sf      = (const float*)d_in[5];
    const float* vf      = (const float*)d_in[6];
    const float* W1      = (const float*)d_in[7];
    const float* b1      = (const float*)d_in[8];
    const float* W2      = (const float*)d_in[9];
    const float* b2      = (const float*)d_in[10];
    const float* Wr      = (const float*)d_in[11];
    const float* br      = (const float*)d_in[12];

    int E = in_sizes[0];
    int N = in_sizes[5] / F;

    float* out_s = (float*)d_out;
    float* out_v = out_s + (size_t)N * F;

    // ---- v4 layout: records path ----
    size_t off = 0;
    auto slab = [&](size_t bytes) { size_t o = off; off = (off + bytes + 255) & ~(size_t)255; return o; };
    size_t o_wrth = slab((size_t)10 * F3 * sizeof(u32));
    size_t o_gbuf = slab((size_t)N * 768 * sizeof(__half));
    size_t o_cnt  = slab((size_t)N * sizeof(int));
    size_t o_row  = slab((size_t)(N + 1) * sizeof(int));
    size_t o_rec  = slab((size_t)E * 64);
    size_t need_v4 = off;

    // ---- v3 layout: edge_order path ----
    size_t off3 = 0;
    auto slab3 = [&](size_t bytes) { size_t o = off3; off3 = (off3 + bytes + 255) & ~(size_t)255; return o; };
    size_t t_wrth = slab3((size_t)10 * F3 * sizeof(u32));
    size_t t_gbuf = slab3((size_t)N * 768 * sizeof(__half));
    size_t t_cnt  = slab3((size_t)N * sizeof(int));
    size_t t_row  = slab3((size_t)(N + 1) * sizeof(int));
    size_t t_ord  = slab3((size_t)E * sizeof(int));
    size_t need_v3 = off3;

    if (ws_size >= need_v4) {
        u32*    WrTh      = (u32*)((char*)d_ws + o_wrth);
        __half* gbufh     = (__half*)((char*)d_ws + o_gbuf);
        u32*    gbuf      = (u32*)gbufh;
        int*    counts    = (int*)((char*)d_ws + o_cnt);
        int*    cursor    = counts;
        int*    row_start = (int*)((char*)d_ws + o_row);
        u32*    recs      = (u32*)((char*)d_ws + o_rec);

        int prep_threads = 10 * F3 + N;
        prep_kernel<<<(prep_threads + 255) / 256, 256, 0, stream>>>(Wr, WrTh, counts, N);
        int PB = (N + NPB - 1) / NPB;
        int HB = (E + 255) / 256;
        int VB = (N + 3) / 4;
        fusedB_kernel<<<PB + HB + VB, 256, 0, stream>>>(sf, W1, b1, W2, b2, idx_i, counts,
                                                        vf, gbufh, N, E, PB, HB);
        if (N <= SCAN_MAXN)
            scan_lds_kernel<<<1, SCAN_T, 0, stream>>>(counts, row_start, cursor, N);
        else
            scan_kernel<<<1, 1024, 0, stream>>>(counts, row_start, cursor, N);
        build_records<<<(E + 255) / 256, 256, 0, stream>>>(idx_i, idx_j, rel_dir, rdc, rbf,
                                                           cursor, recs, E);
        gather4_kernel<<<(N + 1) / 2, 256, 0, stream>>>(sf, vf, WrTh, br, gbuf, recs,
                                                        row_start, out_s, out_v, N);
    } else if (ws_size >= need_v3) {
        u32*    WrTh      = (u32*)((char*)d_ws + t_wrth);
        __half* gbufh     = (__half*)((char*)d_ws + t_gbuf);
        u32*    gbuf      = (u32*)gbufh;
        int*    counts    = (int*)((char*)d_ws + t_cnt);
        int*    cursor    = counts;
        int*    row_start = (int*)((char*)d_ws + t_row);
        int*    edge_ord  = (int*)((char*)d_ws + t_ord);

        int prep_threads = 10 * F3 + N;
        prep_kernel<<<(prep_threads + 255) / 256, 256, 0, stream>>>(Wr, WrTh, counts, N);
        int PB = (N + NPB - 1) / NPB;
        int HB = (E + 255) / 256;
        int VB = (N + 3) / 4;
        fusedB_kernel<<<PB + HB + VB, 256, 0, stream>>>(sf, W1, b1, W2, b2, idx_i, counts,
                                                        vf, gbufh, N, E, PB, HB);
        if (N <= SCAN_MAXN)
            scan_lds_kernel<<<1, SCAN_T, 0, stream>>>(counts, row_start, cursor, N);
        else
            scan_kernel<<<1, 1024, 0, stream>>>(counts, row_start, cursor, N);
        scatter_kernel<<<(E + 255) / 256, 256, 0, stream>>>(idx_i, cursor, edge_ord, E);
        gather3_kernel<<<(N + 1) / 2, 256, 0, stream>>>(idx_j, rel_dir, rdc, rbf, sf, vf,
                                                        WrTh, br, gbuf, row_start, edge_ord,
                                                        out_s, out_v, N);
    } else {
        size_t off2 = 0;
        auto slab2 = [&](size_t bytes) { size_t o = off2; off2 = (off2 + bytes + 255) & ~(size_t)255; return o; };
        size_t f_wrt = slab2((size_t)F3 * NRBF * sizeof(float));
        size_t f_phi = slab2((size_t)N * F3 * sizeof(float));
        float* WrT = (float*)((char*)d_ws + f_wrt);
        float* phi = (float*)((char*)d_ws + f_phi);

        int n_scalar = N * F;
        int n_total  = N * F * 4;
        init_out<<<(n_total / 4 + 255) / 256, 256, 0, stream>>>(sf, vf, (float*)d_out, n_scalar, n_total);
        transpose_wr<<<(F3 * NRBF + 255) / 256, 256, 0, stream>>>(Wr, WrT);
        phi32_kernel<<<(N + NPB - 1) / NPB, 256, 0, stream>>>(sf, W1, b1, W2, b2, phi, N);
        edge_kernel<<<(E + 3) / 4, 256, 0, stream>>>(idx_i, idx_j, rel_dir, rdc, rbf,
                                                     vf, WrT, br, phi, out_s, out_v, E);
    }
}

// Round 7
// 254.790 us; speedup vs baseline: 7.1571x; 1.1309x over previous
//
#include <hip/hip_runtime.h>
#include <hip/hip_fp16.h>

#define F 128
#define F3 384
#define NRBF 20
#define NPB 16
#define CHUNK 64

typedef unsigned int u32;
typedef _Float16 half8 __attribute__((ext_vector_type(8)));
typedef float floatx4 __attribute__((ext_vector_type(4)));

__device__ __forceinline__ float2 uph(u32 u) {
    __half2 h = *(__half2*)&u;
    return __half22float2(h);
}
__device__ __forceinline__ u32 pkh(float a, float b) {
    __half2 h = __floats2half2_rn(a, b);
    return *(u32*)&h;
}

// ---------------- A: pack WrTh + pack Wh (fp16 [F+F3][F]) + zero counts ----------------
__global__ void prep_kernel(const float* __restrict__ Wr,
                            const float* __restrict__ W1, const float* __restrict__ W2,
                            u32* __restrict__ WrTh, _Float16* __restrict__ Wh,
                            int* __restrict__ counts, int n_nodes) {
    int t = blockIdx.x * blockDim.x + threadIdx.x;
    if (t < 10 * F3) {
        int rr = t / F3, f = t % F3;
        WrTh[rr * F3 + f] = pkh(Wr[f * NRBF + 2 * rr], Wr[f * NRBF + 2 * rr + 1]);
        return;
    }
    int u = t - 10 * F3;
    if (u < (F + F3) * F) {
        int n = u >> 7, k = u & (F - 1);
        float w = (n < F) ? W1[n * F + k] : W2[(size_t)(n - F) * F + k];
        Wh[u] = (_Float16)w;
        return;
    }
    int z = u - (F + F3) * F;
    if (z < n_nodes) counts[z] = 0;
}

// ---------------- B: phi via MFMA -> gbuf fp16 slots ----------------
// gbuf slot for feature f: (f&63)*12 + ((f>>6)&1)*6 + (f>>7)
__launch_bounds__(256)
__global__ void phi_mfma_kernel(const float* __restrict__ sf,
                                const _Float16* __restrict__ Wh,
                                const float* __restrict__ b1, const float* __restrict__ b2,
                                __half* __restrict__ gbufh, int n_nodes) {
    __shared__ _Float16 hl[4][16][136];   // per-wave H tile, stride 272B (2-way conflicts only)
    int tid = threadIdx.x;
    int lane = tid & 63;
    int wv = tid >> 6;
    int col = lane & 15;       // fragment col (B n / A m / D n)
    int kg = lane >> 4;        // k-group 0..3
    int row0 = blockIdx.x * 64 + wv * 16;

    // ---- GEMM1: H = silu(X @ W1^T + b1), X rows row0..row0+15 ----
    half8 a1[4];
#pragma unroll
    for (int kb = 0; kb < 4; kb++) {
        int rr = row0 + col;
        if (rr >= n_nodes) rr = n_nodes - 1;
        const float4* xp = (const float4*)(sf + (size_t)rr * F + kb * 32 + kg * 8);
        float4 x0 = xp[0], x1 = xp[1];
        half8 a;
        a[0] = (_Float16)x0.x; a[1] = (_Float16)x0.y; a[2] = (_Float16)x0.z; a[3] = (_Float16)x0.w;
        a[4] = (_Float16)x1.x; a[5] = (_Float16)x1.y; a[6] = (_Float16)x1.z; a[7] = (_Float16)x1.w;
        a1[kb] = a;
    }

    floatx4 acc[8];
#pragma unroll
    for (int nt = 0; nt < 8; nt++) acc[nt] = (floatx4){0.f, 0.f, 0.f, 0.f};
#pragma unroll
    for (int nt = 0; nt < 8; nt++) {
#pragma unroll
        for (int kb = 0; kb < 4; kb++) {
            half8 b = *(const half8*)(Wh + (size_t)(nt * 16 + col) * F + kb * 32 + kg * 8);
            acc[nt] = __builtin_amdgcn_mfma_f32_16x16x32_f16(a1[kb], b, acc[nt], 0, 0, 0);
        }
    }
#pragma unroll
    for (int nt = 0; nt < 8; nt++) {
        int f1 = nt * 16 + col;
        float bb = b1[f1];
#pragma unroll
        for (int r = 0; r < 4; r++) {
            float v = acc[nt][r] + bb;
            float s = v / (1.f + __expf(-v));
            hl[wv][kg * 4 + r][f1] = (_Float16)s;
        }
    }

    // ---- GEMM2: phi = H @ W2^T + b2 (N=384 in 3 chunks of 128) ----
    half8 a2[4];
#pragma unroll
    for (int kb = 0; kb < 4; kb++)
        a2[kb] = *(const half8*)&hl[wv][col][kb * 32 + kg * 8];

#pragma unroll
    for (int c = 0; c < 3; c++) {
#pragma unroll
        for (int nt = 0; nt < 8; nt++) acc[nt] = (floatx4){0.f, 0.f, 0.f, 0.f};
#pragma unroll
        for (int nt = 0; nt < 8; nt++) {
#pragma unroll
            for (int kb = 0; kb < 4; kb++) {
                half8 b = *(const half8*)(Wh + (size_t)(F + c * 128 + nt * 16 + col) * F + kb * 32 + kg * 8);
                acc[nt] = __builtin_amdgcn_mfma_f32_16x16x32_f16(a2[kb], b, acc[nt], 0, 0, 0);
            }
        }
#pragma unroll
        for (int nt = 0; nt < 8; nt++) {
            int f2 = c * 128 + nt * 16 + col;
            float bb = b2[f2];
            int slot = (f2 & 63) * 12 + ((f2 >> 6) & 1) * 6 + (f2 >> 7);
#pragma unroll
            for (int r = 0; r < 4; r++) {
                int node = row0 + kg * 4 + r;
                if (node < n_nodes)
                    gbufh[(size_t)node * 768 + slot] = __float2half(acc[nt][r] + bb);
            }
        }
    }
}

// ---------------- C: fused hist + vf-permute ----------------
__launch_bounds__(256)
__global__ void fusedC_kernel(const int* __restrict__ idx_i, int* __restrict__ counts,
                              const float* __restrict__ vf, __half* __restrict__ gbufh,
                              int n_nodes, int n_edges, int HB) {
    int blk = blockIdx.x, tid = threadIdx.x;
    if (blk < HB) {
        int e = blk * 256 + tid;
        if (e < n_edges) atomicAdd(&counts[idx_i[e]], 1);
    } else {
        int idx = (blk - HB) * 256 + tid;
        int node = idx >> 6, lane = idx & 63;
        if (node < n_nodes) {
            const float* v = vf + (size_t)node * F3;
            __half* g = gbufh + (size_t)node * 768 + lane * 12;
            g[3]  = __float2half(v[lane * 3 + 0]);
            g[4]  = __float2half(v[lane * 3 + 1]);
            g[5]  = __float2half(v[lane * 3 + 2]);
            g[9]  = __float2half(v[(lane + 64) * 3 + 0]);
            g[10] = __float2half(v[(lane + 64) * 3 + 1]);
            g[11] = __float2half(v[(lane + 64) * 3 + 2]);
        }
    }
}

// ---------------- D: LDS-staged single-block exclusive scan ----------------
#define SCAN_T 1024
#define SCAN_MAXN 25600
__launch_bounds__(SCAN_T)
__global__ void scan_lds_kernel(const int* __restrict__ counts, int* __restrict__ row_start,
                                int* __restrict__ cursor, int n) {
    __shared__ int sbuf[SCAN_MAXN];
    __shared__ int partial[SCAN_T];
    int t = threadIdx.x;
    for (int i = t; i < n; i += SCAN_T) sbuf[i] = counts[i];
    __syncthreads();
    int C = (n + SCAN_T - 1) / SCAN_T;
    int beg = t * C, end = min(beg + C, n);
    int sum = 0;
    for (int i = beg; i < end; i++) sum += sbuf[i];
    partial[t] = sum;
    __syncthreads();
    for (int off = 1; off < SCAN_T; off <<= 1) {
        int v = (t >= off) ? partial[t - off] : 0;
        __syncthreads();
        partial[t] += v;
        __syncthreads();
    }
    int base = (t == 0) ? 0 : partial[t - 1];
    for (int i = beg; i < end; i++) { int c = sbuf[i]; sbuf[i] = base; base += c; }
    __syncthreads();
    for (int i = t; i < n; i += SCAN_T) { int v = sbuf[i]; row_start[i] = v; cursor[i] = v; }
    if (t == SCAN_T - 1) row_start[n] = partial[SCAN_T - 1];
}

__launch_bounds__(1024)
__global__ void scan_kernel(const int* __restrict__ counts, int* __restrict__ row_start,
                            int* __restrict__ cursor, int n) {
    __shared__ int partial[1024];
    int t = threadIdx.x;
    int C = (n + 1023) / 1024;
    int beg = t * C, end = min(beg + C, n);
    int sum = 0;
    for (int i = beg; i < end; i++) sum += counts[i];
    partial[t] = sum;
    __syncthreads();
    for (int off = 1; off < 1024; off <<= 1) {
        int v = (t >= off) ? partial[t - off] : 0;
        __syncthreads();
        partial[t] += v;
        __syncthreads();
    }
    int base = (t == 0) ? 0 : partial[t - 1];
    for (int i = beg; i < end; i++) {
        int c = counts[i];
        row_start[i] = base; cursor[i] = base; base += c;
    }
    if (t == 1023) row_start[n] = partial[1023];
}

// ---------------- E: build sorted 64-B edge records ----------------
__global__ void build_records(const int* __restrict__ idx_i, const int* __restrict__ idx_j,
                              const float* __restrict__ rel_dir, const float* __restrict__ rdc,
                              const float* __restrict__ rbf, int* __restrict__ cursor,
                              u32* __restrict__ recs, int n_edges) {
    int e = blockIdx.x * blockDim.x + threadIdx.x;
    if (e >= n_edges) return;
    int p = atomicAdd(&cursor[idx_i[e]], 1);
    u32 r[16];
    r[0] = (u32)idx_j[e];
    r[1] = __float_as_uint(rdc[e]);
    r[2] = __float_as_uint(rel_dir[e * 3 + 0]);
    r[3] = __float_as_uint(rel_dir[e * 3 + 1]);
    r[4] = __float_as_uint(rel_dir[e * 3 + 2]);
    const float* rb = rbf + (size_t)e * NRBF;
#pragma unroll
    for (int t = 0; t < 10; t++) r[5 + t] = pkh(rb[2 * t], rb[2 * t + 1]);
    r[15] = 0;
    float4* dst = (float4*)(recs + (size_t)p * 16);
    const float4* src = (const float4*)r;
    dst[0] = src[0]; dst[1] = src[1]; dst[2] = src[2]; dst[3] = src[3];
}

__global__ void scatter_kernel(const int* __restrict__ idx_i, int* __restrict__ cursor,
                               int* __restrict__ edge_order, int n_edges) {
    int e = blockIdx.x * blockDim.x + threadIdx.x;
    if (e < n_edges) {
        int p = atomicAdd(&cursor[idx_i[e]], 1);
        edge_order[p] = e;
    }
}

// ---------------- F: gather4 — records in LDS, uniform reads, depth-4 pipeline ----------------
__launch_bounds__(256)
__global__ void gather4_kernel(const float* __restrict__ sf, const float* __restrict__ vf,
                               const u32* __restrict__ WrTh, const float* __restrict__ br,
                               const u32* __restrict__ gbuf, const u32* __restrict__ recs,
                               const int* __restrict__ row_start,
                               float* __restrict__ out_s, float* __restrict__ out_v,
                               int n_nodes) {
    __shared__ u32 lsm[4][CHUNK * 16];
    int tid = threadIdx.x;
    int lane = tid & 63;
    int wvid = tid >> 6;
    int w = wvid & 1;
    int node = blockIdx.x * 2 + (wvid >> 1);
    if (node >= n_nodes) return;
    u32* lds = lsm[wvid];

    int fb = lane + 64 * w;
    u32 wrpk[3][10];
    float brv[3];
#pragma unroll
    for (int k = 0; k < 3; k++) {
        brv[k] = br[fb + 128 * k];
#pragma unroll
        for (int rr = 0; rr < 10; rr++)
            wrpk[k][rr] = WrTh[rr * F3 + fb + 128 * k];
    }

    float acc_s = 0.f, av0 = 0.f, av1 = 0.f, av2 = 0.f;
    int beg = row_start[node];
    int end = row_start[node + 1];

    for (int cb = beg; cb < end; cb += CHUNK) {
        int cnt = min(CHUNK, end - cb);
        {
            const float4* src = (const float4*)(recs + (size_t)cb * 16);
            int nf4 = cnt * 4;
            for (int t = lane; t < nf4; t += 64)
                ((float4*)lds)[t] = src[t];
        }

        auto issueL = [&](u32& g0, u32& g1, u32& g2, int m) {
            if (m < cnt) {
                int j = (int)lds[m * 16];
                const u32* gp = gbuf + (size_t)j * 384 + lane * 6 + w * 3;
                g0 = gp[0]; g1 = gp[1]; g2 = gp[2];
            }
        };
        auto computeE = [&](u32 g0, u32 g1, u32 g2, int m) {
            const uint4* q = (const uint4*)(lds + m * 16);
            uint4 q0 = q[0], q1 = q[1], q2 = q[2], q3 = q[3];
            float rd = __uint_as_float(q0.y);
            float dx = __uint_as_float(q0.z);
            float dy = __uint_as_float(q0.w);
            float dz = __uint_as_float(q1.x);
            u32 rbu[10] = { q1.y, q1.z, q1.w, q2.x, q2.y, q2.z, q2.w, q3.x, q3.y, q3.z };
            __half2 z2 = __floats2half2_rn(0.f, 0.f);
            __half2 wa0 = z2, wa1 = z2, wa2 = z2;
#pragma unroll
            for (int rr = 0; rr < 10; rr++) {
                __half2 rbh = *(__half2*)&rbu[rr];
                wa0 = __hfma2(rbh, *(__half2*)&wrpk[0][rr], wa0);
                wa1 = __hfma2(rbh, *(__half2*)&wrpk[1][rr], wa1);
                wa2 = __hfma2(rbh, *(__half2*)&wrpk[2][rr], wa2);
            }
            float W0  = __half2float(wa0.x) + __half2float(wa0.y) + brv[0];
            float W1v = __half2float(wa1.x) + __half2float(wa1.y) + brv[1];
            float W2v = __half2float(wa2.x) + __half2float(wa2.y) + brv[2];
            float2 p01  = uph(g0);
            float2 p2v0 = uph(g1);
            float2 v12  = uph(g2);
            float pw0 = W0  * rd * p01.x;
            float pw1 = W1v * rd * p01.y;
            float pw2 = W2v * rd * p2v0.x;
            acc_s += pw1;
            av0 += p2v0.y * pw0 + pw2 * dx;
            av1 += v12.x  * pw0 + pw2 * dy;
            av2 += v12.y  * pw0 + pw2 * dz;
        };

        u32 A0, A1, A2, B0, B1, B2, C0, C1, C2, D0, D1, D2;
        issueL(A0, A1, A2, 0); issueL(B0, B1, B2, 1);
        issueL(C0, C1, C2, 2); issueL(D0, D1, D2, 3);
        int m = 0;
        while (true) {
            if (m >= cnt) break; computeE(A0, A1, A2, m); m++; issueL(A0, A1, A2, m + 3);
            if (m >= cnt) break; computeE(B0, B1, B2, m); m++; issueL(B0, B1, B2, m + 3);
            if (m >= cnt) break; computeE(C0, C1, C2, m); m++; issueL(C0, C1, C2, m + 3);
            if (m >= cnt) break; computeE(D0, D1, D2, m); m++; issueL(D0, D1, D2, m + 3);
        }
    }

    out_s[(size_t)node * F + fb] = sf[(size_t)node * F + fb] + acc_s;
    const float* vfi = vf + (size_t)node * F3 + fb * 3;
    float* ovi = out_v + (size_t)node * F3 + fb * 3;
    ovi[0] = vfi[0] + av0;
    ovi[1] = vfi[1] + av1;
    ovi[2] = vfi[2] + av2;
}

// ---------------- fallback: gather3 (shfl-based, edge_order) ----------------
__launch_bounds__(256)
__global__ void gather3_kernel(const int* __restrict__ idx_j,
                               const float* __restrict__ rel_dir, const float* __restrict__ rdc,
                               const float* __restrict__ rbf,
                               const float* __restrict__ sf, const float* __restrict__ vf,
                               const u32* __restrict__ WrTh, const float* __restrict__ br,
                               const u32* __restrict__ gbuf,
                               const int* __restrict__ row_start, const int* __restrict__ edge_order,
                               float* __restrict__ out_s, float* __restrict__ out_v,
                               int n_nodes) {
    int lane = threadIdx.x & 63;
    int w = (threadIdx.x >> 6) & 1;
    int node = blockIdx.x * 2 + (threadIdx.x >> 7);
    if (node >= n_nodes) return;

    int fb = lane + 64 * w;
    u32 wrpk[3][10];
    float brv[3];
#pragma unroll
    for (int k = 0; k < 3; k++) {
        brv[k] = br[fb + 128 * k];
#pragma unroll
        for (int rr = 0; rr < 10; rr++)
            wrpk[k][rr] = WrTh[rr * F3 + fb + 128 * k];
    }

    float acc_s = 0.f, av0 = 0.f, av1 = 0.f, av2 = 0.f;
    int beg = row_start[node];
    int end = row_start[node + 1];

    for (int cb = beg; cb < end; cb += 64) {
        int cnt = min(64, end - cb);
        int jv = 0; float rdv = 0.f, dxv = 0.f, dyv = 0.f, dzv = 0.f;
        u32 rbm[10];
#pragma unroll
        for (int rr = 0; rr < 10; rr++) rbm[rr] = 0;
        if (lane < cnt) {
            int e = edge_order[cb + lane];
            jv = idx_j[e];
            rdv = rdc[e];
            dxv = rel_dir[e * 3 + 0]; dyv = rel_dir[e * 3 + 1]; dzv = rel_dir[e * 3 + 2];
            const float4* rp = (const float4*)(rbf + (size_t)e * NRBF);
            float4 r0 = rp[0], r1 = rp[1], r2 = rp[2], r3 = rp[3], r4 = rp[4];
            rbm[0] = pkh(r0.x, r0.y); rbm[1] = pkh(r0.z, r0.w);
            rbm[2] = pkh(r1.x, r1.y); rbm[3] = pkh(r1.z, r1.w);
            rbm[4] = pkh(r2.x, r2.y); rbm[5] = pkh(r2.z, r2.w);
            rbm[6] = pkh(r3.x, r3.y); rbm[7] = pkh(r3.z, r3.w);
            rbm[8] = pkh(r4.x, r4.y); rbm[9] = pkh(r4.z, r4.w);
        }
        auto issue = [&](u32& g0, u32& g1, u32& g2, int k) {
            int j = __shfl(jv, k, 64);
            const u32* gp = gbuf + (size_t)j * 384 + lane * 6 + w * 3;
            g0 = gp[0]; g1 = gp[1]; g2 = gp[2];
        };
        auto compute = [&](u32 g0, u32 g1, u32 g2, int k) {
            float rd = __shfl(rdv, k, 64);
            float dx = __shfl(dxv, k, 64);
            float dy = __shfl(dyv, k, 64);
            float dz = __shfl(dzv, k, 64);
            __half2 z2 = __floats2half2_rn(0.f, 0.f);
            __half2 wa0 = z2, wa1 = z2, wa2 = z2;
#pragma unroll
            for (int rr = 0; rr < 10; rr++) {
                int rbi = __shfl((int)rbm[rr], k, 64);
                __half2 rbh = *(__half2*)&rbi;
                wa0 = __hfma2(rbh, *(__half2*)&wrpk[0][rr], wa0);
                wa1 = __hfma2(rbh, *(__half2*)&wrpk[1][rr], wa1);
                wa2 = __hfma2(rbh, *(__half2*)&wrpk[2][rr], wa2);
            }
            float W0 = __half2float(wa0.x) + __half2float(wa0.y) + brv[0];
            float W1v = __half2float(wa1.x) + __half2float(wa1.y) + brv[1];
            float W2v = __half2float(wa2.x) + __half2float(wa2.y) + brv[2];
            float2 p01 = uph(g0);
            float2 p2v0 = uph(g1);
            float2 v12 = uph(g2);
            float pw0 = W0 * rd * p01.x;
            float pw1 = W1v * rd * p01.y;
            float pw2 = W2v * rd * p2v0.x;
            acc_s += pw1;
            av0 += p2v0.y * pw0 + pw2 * dx;
            av1 += v12.x  * pw0 + pw2 * dy;
            av2 += v12.y  * pw0 + pw2 * dz;
        };
        u32 A0, A1, A2, B0, B1, B2;
        issue(A0, A1, A2, 0);
        int k = 0;
        while (k + 2 <= cnt) {
            issue(B0, B1, B2, k + 1);
            compute(A0, A1, A2, k);
            if (k + 2 < cnt) issue(A0, A1, A2, k + 2);
            compute(B0, B1, B2, k + 1);
            k += 2;
        }
        if (k < cnt) compute(A0, A1, A2, k);
    }

    out_s[(size_t)node * F + fb] = sf[(size_t)node * F + fb] + acc_s;
    const float* vfi = vf + (size_t)node * F3 + fb * 3;
    float* ovi = out_v + (size_t)node * F3 + fb * 3;
    ovi[0] = vfi[0] + av0;
    ovi[1] = vfi[1] + av1;
    ovi[2] = vfi[2] + av2;
}

// ---------------- tiny-ws fallback ----------------
__global__ void transpose_wr(const float* __restrict__ Wr, float* __restrict__ WrT) {
    int idx = blockIdx.x * blockDim.x + threadIdx.x;
    if (idx < F3 * NRBF) {
        int f = idx / NRBF, r = idx % NRBF;
        WrT[r * F3 + f] = Wr[idx];
    }
}

__global__ void init_out(const float* __restrict__ sf, const float* __restrict__ vf,
                         float* __restrict__ out, int n_scalar, int n_total) {
    int i = blockIdx.x * blockDim.x + threadIdx.x;
    int n4 = n_total >> 2;
    if (i < n4) {
        float4 v;
        int base = i << 2;
        if (base < n_scalar) v = ((const float4*)sf)[i];
        else                 v = ((const float4*)vf)[i - (n_scalar >> 2)];
        ((float4*)out)[i] = v;
    }
}

__launch_bounds__(256)
__global__ void phi32_kernel(const float* __restrict__ sf,
                             const float* __restrict__ W1, const float* __restrict__ b1,
                             const float* __restrict__ W2, const float* __restrict__ b2,
                             float* __restrict__ phi, int n_nodes) {
    __shared__ float xs[NPB][F];
    __shared__ float hs[NPB][F];
    int tid = threadIdx.x;
    int nb = blockIdx.x * NPB;
    for (int t = tid; t < NPB * F / 4; t += 256) {
        int n  = t / (F / 4);
        int k4 = t % (F / 4);
        float4 v = make_float4(0.f, 0.f, 0.f, 0.f);
        if (nb + n < n_nodes) v = ((const float4*)(sf + (size_t)(nb + n) * F))[k4];
        ((float4*)&xs[n][0])[k4] = v;
    }
    __syncthreads();
    {
        int f = tid & (F - 1);
        int half_ = tid >> 7;
        float acc[8];
#pragma unroll
        for (int nn = 0; nn < 8; nn++) acc[nn] = 0.f;
        const float* w1row = W1 + (size_t)f * F;
        for (int k = 0; k < F; k++) {
            float w = w1row[k];
#pragma unroll
            for (int nn = 0; nn < 8; nn++)
                acc[nn] += xs[half_ * 8 + nn][k] * w;
        }
        float b = b1[f];
#pragma unroll
        for (int nn = 0; nn < 8; nn++) {
            float v = acc[nn] + b;
            hs[half_ * 8 + nn][f] = v / (1.f + __expf(-v));
        }
    }
    __syncthreads();
    for (int f = tid; f < F3; f += 256) {
        float acc[NPB];
#pragma unroll
        for (int n = 0; n < NPB; n++) acc[n] = 0.f;
        const float* w2row = W2 + (size_t)f * F;
        for (int k = 0; k < F; k++) {
            float w = w2row[k];
#pragma unroll
            for (int n = 0; n < NPB; n++)
                acc[n] += hs[n][k] * w;
        }
        float b = b2[f];
        for (int n = 0; n < NPB; n++)
            if (nb + n < n_nodes)
                phi[(size_t)(nb + n) * F3 + f] = acc[n] + b;
    }
}

__launch_bounds__(256)
__global__ void edge_kernel(const int* __restrict__ idx_i, const int* __restrict__ idx_j,
                            const float* __restrict__ rel_dir, const float* __restrict__ rdc,
                            const float* __restrict__ rbf,
                            const float* __restrict__ vf,
                            const float* __restrict__ WrT, const float* __restrict__ br,
                            const float* __restrict__ phi,
                            float* __restrict__ out_s, float* __restrict__ out_v,
                            int n_edges) {
    int lane = threadIdx.x & 63;
    int e = (int)((blockIdx.x * (unsigned)blockDim.x + threadIdx.x) >> 6);
    if (e >= n_edges) return;
    int i = idx_i[e], j = idx_j[e];
    float rd = rdc[e];
    float d0 = rel_dir[e * 3 + 0], d1 = rel_dir[e * 3 + 1], d2 = rel_dir[e * 3 + 2];
    float rb[NRBF];
#pragma unroll
    for (int r = 0; r < NRBF; r++) rb[r] = rbf[(size_t)e * NRBF + r];
    const float* pj = phi + (size_t)j * F3;
    float pw[6];
#pragma unroll
    for (int q = 0; q < 6; q++) {
        int f = lane + 64 * q;
        float acc = br[f];
#pragma unroll
        for (int r = 0; r < NRBF; r++)
            acc += rb[r] * WrT[r * F3 + f];
        pw[q] = acc * rd * pj[f];
    }
    atomicAdd(&out_s[(size_t)i * F + lane],       pw[2]);
    atomicAdd(&out_s[(size_t)i * F + lane + 64],  pw[3]);
    const float* vfj = vf + (size_t)j * F * 3;
    float* ovi = out_v + (size_t)i * F * 3;
#pragma unroll
    for (int h = 0; h < 2; h++) {
        int f = lane + 64 * h;
        float vv = pw[h];
        float vs = pw[4 + h];
        atomicAdd(&ovi[f * 3 + 0], vfj[f * 3 + 0] * vv + vs * d0);
        atomicAdd(&ovi[f * 3 + 1], vfj[f * 3 + 1] * vv + vs * d1);
        atomicAdd(&ovi[f * 3 + 2], vfj[f * 3 + 2] * vv + vs * d2);
    }
}

extern "C" void kernel_launch(void* const* d_in, const int* in_sizes, int n_in,
                              void* d_out, int out_size, void* d_ws, size_t ws_size,
                              hipStream_t stream) {
    const int*   idx_i   = (const int*)d_in[0];
    const int*   idx_j   = (const int*)d_in[1];
    const float* rel_dir = (const float*)d_in[2];
    const float* rdc     = (const float*)d_in[3];
    const float* rbf     = (const float*)d_in[4];
    const float* sf      = (const float*)d_in[5];
    const float* vf      = (const float*)d_in[6];
    const float* W1      = (const float*)d_in[7];
    const float* b1      = (const float*)d_in[8];
    const float* W2      = (const float*)d_in[9];
    const float* b2      = (const float*)d_in[10];
    const float* Wr      = (const float*)d_in[11];
    const float* br      = (const float*)d_in[12];

    int E = in_sizes[0];
    int N = in_sizes[5] / F;

    float* out_s = (float*)d_out;
    float* out_v = out_s + (size_t)N * F;

    // ---- v5 layout: MFMA phi + records ----
    size_t off = 0;
    auto slab = [&](size_t bytes) { size_t o = off; off = (off + bytes + 255) & ~(size_t)255; return o; };
    size_t o_wrth = slab((size_t)10 * F3 * sizeof(u32));
    size_t o_wh   = slab((size_t)(F + F3) * F * sizeof(_Float16));
    size_t o_gbuf = slab((size_t)N * 768 * sizeof(__half));
    size_t o_cnt  = slab((size_t)N * sizeof(int));
    size_t o_row  = slab((size_t)(N + 1) * sizeof(int));
    size_t o_rec  = slab((size_t)E * 64);
    size_t need_v5 = off;

    // ---- v3 layout: MFMA phi + edge_order (smaller) ----
    size_t off3 = 0;
    auto slab3 = [&](size_t bytes) { size_t o = off3; off3 = (off3 + bytes + 255) & ~(size_t)255; return o; };
    size_t t_wrth = slab3((size_t)10 * F3 * sizeof(u32));
    size_t t_wh   = slab3((size_t)(F + F3) * F * sizeof(_Float16));
    size_t t_gbuf = slab3((size_t)N * 768 * sizeof(__half));
    size_t t_cnt  = slab3((size_t)N * sizeof(int));
    size_t t_row  = slab3((size_t)(N + 1) * sizeof(int));
    size_t t_ord  = slab3((size_t)E * sizeof(int));
    size_t need_v3 = off3;

    int prep_threads = 10 * F3 + (F + F3) * F + N;
    int HB = (E + 255) / 256;
    int VB = (N + 3) / 4;
    int PHB = (N + 63) / 64;

    if (ws_size >= need_v5) {
        u32*      WrTh      = (u32*)((char*)d_ws + o_wrth);
        _Float16* Wh        = (_Float16*)((char*)d_ws + o_wh);
        __half*   gbufh     = (__half*)((char*)d_ws + o_gbuf);
        u32*      gbuf      = (u32*)gbufh;
        int*      counts    = (int*)((char*)d_ws + o_cnt);
        int*      cursor    = counts;
        int*      row_start = (int*)((char*)d_ws + o_row);
        u32*      recs      = (u32*)((char*)d_ws + o_rec);

        prep_kernel<<<(prep_threads + 255) / 256, 256, 0, stream>>>(Wr, W1, W2, WrTh, Wh, counts, N);
        phi_mfma_kernel<<<PHB, 256, 0, stream>>>(sf, Wh, b1, b2, gbufh, N);
        fusedC_kernel<<<HB + VB, 256, 0, stream>>>(idx_i, counts, vf, gbufh, N, E, HB);
        if (N <= SCAN_MAXN)
            scan_lds_kernel<<<1, SCAN_T, 0, stream>>>(counts, row_start, cursor, N);
        else
            scan_kernel<<<1, 1024, 0, stream>>>(counts, row_start, cursor, N);
        build_records<<<(E + 255) / 256, 256, 0, stream>>>(idx_i, idx_j, rel_dir, rdc, rbf,
                                                           cursor, recs, E);
        gather4_kernel<<<(N + 1) / 2, 256, 0, stream>>>(sf, vf, WrTh, br, gbuf, recs,
                                                        row_start, out_s, out_v, N);
    } else if (ws_size >= need_v3) {
        u32*      WrTh      = (u32*)((char*)d_ws + t_wrth);
        _Float16* Wh        = (_Float16*)((char*)d_ws + t_wh);
        __half*   gbufh     = (__half*)((char*)d_ws + t_gbuf);
        u32*      gbuf      = (u32*)gbufh;
        int*      counts    = (int*)((char*)d_ws + t_cnt);
        int*      cursor    = counts;
        int*      row_start = (int*)((char*)d_ws + t_row);
        int*      edge_ord  = (int*)((char*)d_ws + t_ord);

        prep_kernel<<<(prep_threads + 255) / 256, 256, 0, stream>>>(Wr, W1, W2, WrTh, Wh, counts, N);
        phi_mfma_kernel<<<PHB, 256, 0, stream>>>(sf, Wh, b1, b2, gbufh, N);
        fusedC_kernel<<<HB + VB, 256, 0, stream>>>(idx_i, counts, vf, gbufh, N, E, HB);
        if (N <= SCAN_MAXN)
            scan_lds_kernel<<<1, SCAN_T, 0, stream>>>(counts, row_start, cursor, N);
        else
            scan_kernel<<<1, 1024, 0, stream>>>(counts, row_start, cursor, N);
        scatter_kernel<<<(E + 255) / 256, 256, 0, stream>>>(idx_i, cursor, edge_ord, E);
        gather3_kernel<<<(N + 1) / 2, 256, 0, stream>>>(idx_j, rel_dir, rdc, rbf, sf, vf,
                                                        WrTh, br, gbuf, row_start, edge_ord,
                                                        out_s, out_v, N);
    } else {
        size_t off2 = 0;
        auto slab2 = [&](size_t bytes) { size_t o = off2; off2 = (off2 + bytes + 255) & ~(size_t)255; return o; };
        size_t f_wrt = slab2((size_t)F3 * NRBF * sizeof(float));
        size_t f_phi = slab2((size_t)N * F3 * sizeof(float));
        float* WrT = (float*)((char*)d_ws + f_wrt);
        float* phi = (float*)((char*)d_ws + f_phi);

        int n_scalar = N * F;
        int n_total  = N * F * 4;
        init_out<<<(n_total / 4 + 255) / 256, 256, 0, stream>>>(sf, vf, (float*)d_out, n_scalar, n_total);
        transpose_wr<<<(F3 * NRBF + 255) / 256, 256, 0, stream>>>(Wr, WrT);
        phi32_kernel<<<(N + NPB - 1) / NPB, 256, 0, stream>>>(sf, W1, b1, W2, b2, phi, N);
        edge_kernel<<<(E + 3) / 4, 256, 0, stream>>>(idx_i, idx_j, rel_dir, rdc, rbf,
                                                     vf, WrT, br, phi, out_s, out_v, E);
    }
}

// Round 8
// 233.624 us; speedup vs baseline: 7.8055x; 1.0906x over previous
//
#include <hip/hip_runtime.h>
#include <hip/hip_fp16.h>

#define F 128
#define F3 384
#define NRBF 20
#define NPB 16
#define CHUNK 64

typedef unsigned int u32;
typedef _Float16 half8 __attribute__((ext_vector_type(8)));
typedef float floatx4 __attribute__((ext_vector_type(4)));

__device__ __forceinline__ float2 uph(u32 u) {
    __half2 h = *(__half2*)&u;
    return __half22float2(h);
}
__device__ __forceinline__ u32 pkh(float a, float b) {
    __half2 h = __floats2half2_rn(a, b);
    return *(u32*)&h;
}

// fp16x2 dot with f32 accumulate — v_dot2_f32_f16 when available
__device__ __forceinline__ float fdot2f(u32 a, u32 b, float c) {
#if defined(__has_builtin)
#if __has_builtin(__builtin_amdgcn_fdot2)
    typedef _Float16 h2 __attribute__((ext_vector_type(2)));
    return __builtin_amdgcn_fdot2(*(h2*)&a, *(h2*)&b, c, false);
#else
    float2 fa = uph(a), fb = uph(b);
    return fmaf(fa.x, fb.x, fmaf(fa.y, fb.y, c));
#endif
#else
    float2 fa = uph(a), fb = uph(b);
    return fmaf(fa.x, fb.x, fmaf(fa.y, fb.y, c));
#endif
}

// ---------------- A: pack WrTh + pack Wh (fp16 [F+F3][F]) + zero counts ----------------
__global__ void prep_kernel(const float* __restrict__ Wr,
                            const float* __restrict__ W1, const float* __restrict__ W2,
                            u32* __restrict__ WrTh, _Float16* __restrict__ Wh,
                            int* __restrict__ counts, int n_nodes) {
    int t = blockIdx.x * blockDim.x + threadIdx.x;
    if (t < 10 * F3) {
        int rr = t / F3, f = t % F3;
        WrTh[rr * F3 + f] = pkh(Wr[f * NRBF + 2 * rr], Wr[f * NRBF + 2 * rr + 1]);
        return;
    }
    int u = t - 10 * F3;
    if (u < (F + F3) * F) {
        int n = u >> 7, k = u & (F - 1);
        float w = (n < F) ? W1[n * F + k] : W2[(size_t)(n - F) * F + k];
        Wh[u] = (_Float16)w;
        return;
    }
    int z = u - (F + F3) * F;
    if (z < n_nodes) counts[z] = 0;
}

// ---------------- B: fused phi-MFMA + vf-permute + hist ----------------
// phi blocks: blk < PHB (64 nodes each); hist blocks: the rest.
// gbuf trio slot for feature f: (f&63)*12 + ((f>>6)&1)*6 + (f>>7); vf at +3..5 within each 6.
__launch_bounds__(256)
__global__ void fusedB2_kernel(const float* __restrict__ sf,
                               const _Float16* __restrict__ Wh,
                               const float* __restrict__ b1, const float* __restrict__ b2,
                               const float* __restrict__ vf, __half* __restrict__ gbufh,
                               const int* __restrict__ idx_i, int* __restrict__ counts,
                               int n_nodes, int n_edges, int PHB) {
    __shared__ _Float16 hl[4][16][136];
    int blk = blockIdx.x, tid = threadIdx.x;

    if (blk >= PHB) {
        int e = (blk - PHB) * 256 + tid;
        if (e < n_edges) atomicAdd(&counts[idx_i[e]], 1);
        return;
    }

    int lane = tid & 63;
    int wv = tid >> 6;
    int col = lane & 15;
    int kg = lane >> 4;
    int row0 = blk * 64 + wv * 16;

    // ---- GEMM1: H = silu(X @ W1^T + b1) ----
    half8 a1[4];
#pragma unroll
    for (int kb = 0; kb < 4; kb++) {
        int rr = row0 + col;
        if (rr >= n_nodes) rr = n_nodes - 1;
        const float4* xp = (const float4*)(sf + (size_t)rr * F + kb * 32 + kg * 8);
        float4 x0 = xp[0], x1 = xp[1];
        half8 a;
        a[0] = (_Float16)x0.x; a[1] = (_Float16)x0.y; a[2] = (_Float16)x0.z; a[3] = (_Float16)x0.w;
        a[4] = (_Float16)x1.x; a[5] = (_Float16)x1.y; a[6] = (_Float16)x1.z; a[7] = (_Float16)x1.w;
        a1[kb] = a;
    }

    floatx4 acc[8];
#pragma unroll
    for (int nt = 0; nt < 8; nt++) acc[nt] = (floatx4){0.f, 0.f, 0.f, 0.f};
#pragma unroll
    for (int nt = 0; nt < 8; nt++) {
#pragma unroll
        for (int kb = 0; kb < 4; kb++) {
            half8 b = *(const half8*)(Wh + (size_t)(nt * 16 + col) * F + kb * 32 + kg * 8);
            acc[nt] = __builtin_amdgcn_mfma_f32_16x16x32_f16(a1[kb], b, acc[nt], 0, 0, 0);
        }
    }
#pragma unroll
    for (int nt = 0; nt < 8; nt++) {
        int f1 = nt * 16 + col;
        float bb = b1[f1];
#pragma unroll
        for (int r = 0; r < 4; r++) {
            float v = acc[nt][r] + bb;
            float s = v / (1.f + __expf(-v));
            hl[wv][kg * 4 + r][f1] = (_Float16)s;
        }
    }

    // ---- GEMM2: phi = H @ W2^T + b2 ----
    half8 a2[4];
#pragma unroll
    for (int kb = 0; kb < 4; kb++)
        a2[kb] = *(const half8*)&hl[wv][col][kb * 32 + kg * 8];

#pragma unroll
    for (int c = 0; c < 3; c++) {
#pragma unroll
        for (int nt = 0; nt < 8; nt++) acc[nt] = (floatx4){0.f, 0.f, 0.f, 0.f};
#pragma unroll
        for (int nt = 0; nt < 8; nt++) {
#pragma unroll
            for (int kb = 0; kb < 4; kb++) {
                half8 b = *(const half8*)(Wh + (size_t)(F + c * 128 + nt * 16 + col) * F + kb * 32 + kg * 8);
                acc[nt] = __builtin_amdgcn_mfma_f32_16x16x32_f16(a2[kb], b, acc[nt], 0, 0, 0);
            }
        }
#pragma unroll
        for (int nt = 0; nt < 8; nt++) {
            int f2 = c * 128 + nt * 16 + col;
            float bb = b2[f2];
            int slot = (f2 & 63) * 12 + ((f2 >> 6) & 1) * 6 + (f2 >> 7);
#pragma unroll
            for (int r = 0; r < 4; r++) {
                int node = row0 + kg * 4 + r;
                if (node < n_nodes)
                    gbufh[(size_t)node * 768 + slot] = __float2half(acc[nt][r] + bb);
            }
        }
    }

    // ---- vf epilogue: permute vf for this block's 64 nodes into gbuf slots 3..5 / 9..11 ----
    int base = blk * 64;
    for (int idx = tid; idx < 64 * 64; idx += 256) {
        int nl = idx >> 6, ln = idx & 63;
        int node = base + nl;
        if (node < n_nodes) {
            const float* v = vf + (size_t)node * F3;
            u32* gp = (u32*)(gbufh + (size_t)node * 768 + ln * 12);
            float a0 = v[ln * 3 + 0], a1v = v[ln * 3 + 1], a2v = v[ln * 3 + 2];
            float c0 = v[(ln + 64) * 3 + 0], c1 = v[(ln + 64) * 3 + 1], c2 = v[(ln + 64) * 3 + 2];
            ((__half*)gp)[3] = __float2half(a0);
            gp[2] = pkh(a1v, a2v);
            ((__half*)gp)[9] = __float2half(c0);
            gp[5] = pkh(c1, c2);
        }
    }
}

// ---------------- C: LDS-staged single-block exclusive scan ----------------
#define SCAN_T 1024
#define SCAN_MAXN 25600
__launch_bounds__(SCAN_T)
__global__ void scan_lds_kernel(const int* __restrict__ counts, int* __restrict__ row_start,
                                int* __restrict__ cursor, int n) {
    __shared__ int sbuf[SCAN_MAXN];
    __shared__ int partial[SCAN_T];
    int t = threadIdx.x;
    for (int i = t; i < n; i += SCAN_T) sbuf[i] = counts[i];
    __syncthreads();
    int C = (n + SCAN_T - 1) / SCAN_T;
    int beg = t * C, end = min(beg + C, n);
    int sum = 0;
    for (int i = beg; i < end; i++) sum += sbuf[i];
    partial[t] = sum;
    __syncthreads();
    for (int off = 1; off < SCAN_T; off <<= 1) {
        int v = (t >= off) ? partial[t - off] : 0;
        __syncthreads();
        partial[t] += v;
        __syncthreads();
    }
    int base = (t == 0) ? 0 : partial[t - 1];
    for (int i = beg; i < end; i++) { int c = sbuf[i]; sbuf[i] = base; base += c; }
    __syncthreads();
    for (int i = t; i < n; i += SCAN_T) { int v = sbuf[i]; row_start[i] = v; cursor[i] = v; }
    if (t == SCAN_T - 1) row_start[n] = partial[SCAN_T - 1];
}

__launch_bounds__(1024)
__global__ void scan_kernel(const int* __restrict__ counts, int* __restrict__ row_start,
                            int* __restrict__ cursor, int n) {
    __shared__ int partial[1024];
    int t = threadIdx.x;
    int C = (n + 1023) / 1024;
    int beg = t * C, end = min(beg + C, n);
    int sum = 0;
    for (int i = beg; i < end; i++) sum += counts[i];
    partial[t] = sum;
    __syncthreads();
    for (int off = 1; off < 1024; off <<= 1) {
        int v = (t >= off) ? partial[t - off] : 0;
        __syncthreads();
        partial[t] += v;
        __syncthreads();
    }
    int base = (t == 0) ? 0 : partial[t - 1];
    for (int i = beg; i < end; i++) {
        int c = counts[i];
        row_start[i] = base; cursor[i] = base; base += c;
    }
    if (t == 1023) row_start[n] = partial[1023];
}

// ---------------- D: build sorted 64-B edge records ----------------
__global__ void build_records(const int* __restrict__ idx_i, const int* __restrict__ idx_j,
                              const float* __restrict__ rel_dir, const float* __restrict__ rdc,
                              const float* __restrict__ rbf, int* __restrict__ cursor,
                              u32* __restrict__ recs, int n_edges) {
    int e = blockIdx.x * blockDim.x + threadIdx.x;
    if (e >= n_edges) return;
    int p = atomicAdd(&cursor[idx_i[e]], 1);
    u32 r[16];
    r[0] = (u32)idx_j[e];
    r[1] = __float_as_uint(rdc[e]);
    r[2] = __float_as_uint(rel_dir[e * 3 + 0]);
    r[3] = __float_as_uint(rel_dir[e * 3 + 1]);
    r[4] = __float_as_uint(rel_dir[e * 3 + 2]);
    const float* rb = rbf + (size_t)e * NRBF;
#pragma unroll
    for (int t = 0; t < 10; t++) r[5 + t] = pkh(rb[2 * t], rb[2 * t + 1]);
    r[15] = 0;
    float4* dst = (float4*)(recs + (size_t)p * 16);
    const float4* src = (const float4*)r;
    dst[0] = src[0]; dst[1] = src[1]; dst[2] = src[2]; dst[3] = src[3];
}

__global__ void scatter_kernel(const int* __restrict__ idx_i, int* __restrict__ cursor,
                               int* __restrict__ edge_order, int n_edges) {
    int e = blockIdx.x * blockDim.x + threadIdx.x;
    if (e < n_edges) {
        int p = atomicAdd(&cursor[idx_i[e]], 1);
        edge_order[p] = e;
    }
}

// ---------------- E: gather5 — fdot2 W-dot, records in LDS, depth-4 pipeline ----------------
__launch_bounds__(256)
__global__ void gather5_kernel(const float* __restrict__ sf, const float* __restrict__ vf,
                               const u32* __restrict__ WrTh, const float* __restrict__ br,
                               const u32* __restrict__ gbuf, const u32* __restrict__ recs,
                               const int* __restrict__ row_start,
                               float* __restrict__ out_s, float* __restrict__ out_v,
                               int n_nodes) {
    __shared__ u32 lsm[4][CHUNK * 16];
    int tid = threadIdx.x;
    int lane = tid & 63;
    int wvid = tid >> 6;
    int w = wvid & 1;
    int node = blockIdx.x * 2 + (wvid >> 1);
    if (node >= n_nodes) return;
    u32* lds = lsm[wvid];

    int fb = lane + 64 * w;
    u32 wrpk[3][10];
    float brv[3];
#pragma unroll
    for (int k = 0; k < 3; k++) {
        brv[k] = br[fb + 128 * k];
#pragma unroll
        for (int rr = 0; rr < 10; rr++)
            wrpk[k][rr] = WrTh[rr * F3 + fb + 128 * k];
    }

    float acc_s = 0.f, av0 = 0.f, av1 = 0.f, av2 = 0.f;
    int beg = row_start[node];
    int end = row_start[node + 1];

    for (int cb = beg; cb < end; cb += CHUNK) {
        int cnt = min(CHUNK, end - cb);
        {
            const float4* src = (const float4*)(recs + (size_t)cb * 16);
            int nf4 = cnt * 4;
            for (int t = lane; t < nf4; t += 64)
                ((float4*)lds)[t] = src[t];
        }

        auto issueL = [&](u32& g0, u32& g1, u32& g2, int m) {
            if (m < cnt) {
                int j = (int)lds[m * 16];
                const u32* gp = gbuf + (size_t)j * 384 + lane * 6 + w * 3;
                g0 = gp[0]; g1 = gp[1]; g2 = gp[2];
            }
        };
        auto computeE = [&](u32 g0, u32 g1, u32 g2, int m) {
            const uint4* q = (const uint4*)(lds + m * 16);
            uint4 q0 = q[0], q1 = q[1], q2 = q[2], q3 = q[3];
            float rd = __uint_as_float(q0.y);
            float dx = __uint_as_float(q0.z);
            float dy = __uint_as_float(q0.w);
            float dz = __uint_as_float(q1.x);
            u32 rbu[10] = { q1.y, q1.z, q1.w, q2.x, q2.y, q2.z, q2.w, q3.x, q3.y, q3.z };
            float W0 = brv[0], W1f = brv[1], W2f = brv[2];
#pragma unroll
            for (int rr = 0; rr < 10; rr++) {
                W0  = fdot2f(rbu[rr], wrpk[0][rr], W0);
                W1f = fdot2f(rbu[rr], wrpk[1][rr], W1f);
                W2f = fdot2f(rbu[rr], wrpk[2][rr], W2f);
            }
            float2 p01  = uph(g0);   // phi k0, k1
            float2 p2v0 = uph(g1);   // phi k2, vf c0
            float2 v12  = uph(g2);   // vf c1, c2
            float pw0 = W0  * rd * p01.x;
            float pw1 = W1f * rd * p01.y;
            float pw2 = W2f * rd * p2v0.x;
            acc_s += pw1;
            av0 += p2v0.y * pw0 + pw2 * dx;
            av1 += v12.x  * pw0 + pw2 * dy;
            av2 += v12.y  * pw0 + pw2 * dz;
        };

        u32 A0, A1, A2, B0, B1, B2, C0, C1, C2, D0, D1, D2;
        issueL(A0, A1, A2, 0); issueL(B0, B1, B2, 1);
        issueL(C0, C1, C2, 2); issueL(D0, D1, D2, 3);
        int m = 0;
        while (true) {
            if (m >= cnt) break; computeE(A0, A1, A2, m); m++; issueL(A0, A1, A2, m + 3);
            if (m >= cnt) break; computeE(B0, B1, B2, m); m++; issueL(B0, B1, B2, m + 3);
            if (m >= cnt) break; computeE(C0, C1, C2, m); m++; issueL(C0, C1, C2, m + 3);
            if (m >= cnt) break; computeE(D0, D1, D2, m); m++; issueL(D0, D1, D2, m + 3);
        }
    }

    out_s[(size_t)node * F + fb] = sf[(size_t)node * F + fb] + acc_s;
    const float* vfi = vf + (size_t)node * F3 + fb * 3;
    float* ovi = out_v + (size_t)node * F3 + fb * 3;
    ovi[0] = vfi[0] + av0;
    ovi[1] = vfi[1] + av1;
    ovi[2] = vfi[2] + av2;
}

// ---------------- fallback: gather3 (shfl-based, edge_order) ----------------
__launch_bounds__(256)
__global__ void gather3_kernel(const int* __restrict__ idx_j,
                               const float* __restrict__ rel_dir, const float* __restrict__ rdc,
                               const float* __restrict__ rbf,
                               const float* __restrict__ sf, const float* __restrict__ vf,
                               const u32* __restrict__ WrTh, const float* __restrict__ br,
                               const u32* __restrict__ gbuf,
                               const int* __restrict__ row_start, const int* __restrict__ edge_order,
                               float* __restrict__ out_s, float* __restrict__ out_v,
                               int n_nodes) {
    int lane = threadIdx.x & 63;
    int w = (threadIdx.x >> 6) & 1;
    int node = blockIdx.x * 2 + (threadIdx.x >> 7);
    if (node >= n_nodes) return;

    int fb = lane + 64 * w;
    u32 wrpk[3][10];
    float brv[3];
#pragma unroll
    for (int k = 0; k < 3; k++) {
        brv[k] = br[fb + 128 * k];
#pragma unroll
        for (int rr = 0; rr < 10; rr++)
            wrpk[k][rr] = WrTh[rr * F3 + fb + 128 * k];
    }

    float acc_s = 0.f, av0 = 0.f, av1 = 0.f, av2 = 0.f;
    int beg = row_start[node];
    int end = row_start[node + 1];

    for (int cb = beg; cb < end; cb += 64) {
        int cnt = min(64, end - cb);
        int jv = 0; float rdv = 0.f, dxv = 0.f, dyv = 0.f, dzv = 0.f;
        u32 rbm[10];
#pragma unroll
        for (int rr = 0; rr < 10; rr++) rbm[rr] = 0;
        if (lane < cnt) {
            int e = edge_order[cb + lane];
            jv = idx_j[e];
            rdv = rdc[e];
            dxv = rel_dir[e * 3 + 0]; dyv = rel_dir[e * 3 + 1]; dzv = rel_dir[e * 3 + 2];
            const float4* rp = (const float4*)(rbf + (size_t)e * NRBF);
            float4 r0 = rp[0], r1 = rp[1], r2 = rp[2], r3 = rp[3], r4 = rp[4];
            rbm[0] = pkh(r0.x, r0.y); rbm[1] = pkh(r0.z, r0.w);
            rbm[2] = pkh(r1.x, r1.y); rbm[3] = pkh(r1.z, r1.w);
            rbm[4] = pkh(r2.x, r2.y); rbm[5] = pkh(r2.z, r2.w);
            rbm[6] = pkh(r3.x, r3.y); rbm[7] = pkh(r3.z, r3.w);
            rbm[8] = pkh(r4.x, r4.y); rbm[9] = pkh(r4.z, r4.w);
        }
        auto issue = [&](u32& g0, u32& g1, u32& g2, int k) {
            int j = __shfl(jv, k, 64);
            const u32* gp = gbuf + (size_t)j * 384 + lane * 6 + w * 3;
            g0 = gp[0]; g1 = gp[1]; g2 = gp[2];
        };
        auto compute = [&](u32 g0, u32 g1, u32 g2, int k) {
            float rd = __shfl(rdv, k, 64);
            float dx = __shfl(dxv, k, 64);
            float dy = __shfl(dyv, k, 64);
            float dz = __shfl(dzv, k, 64);
            float W0 = brv[0], W1f = brv[1], W2f = brv[2];
#pragma unroll
            for (int rr = 0; rr < 10; rr++) {
                u32 rbi = (u32)__shfl((int)rbm[rr], k, 64);
                W0  = fdot2f(rbi, wrpk[0][rr], W0);
                W1f = fdot2f(rbi, wrpk[1][rr], W1f);
                W2f = fdot2f(rbi, wrpk[2][rr], W2f);
            }
            float2 p01 = uph(g0);
            float2 p2v0 = uph(g1);
            float2 v12 = uph(g2);
            float pw0 = W0 * rd * p01.x;
            float pw1 = W1f * rd * p01.y;
            float pw2 = W2f * rd * p2v0.x;
            acc_s += pw1;
            av0 += p2v0.y * pw0 + pw2 * dx;
            av1 += v12.x  * pw0 + pw2 * dy;
            av2 += v12.y  * pw0 + pw2 * dz;
        };
        u32 A0, A1, A2, B0, B1, B2;
        issue(A0, A1, A2, 0);
        int k = 0;
        while (k + 2 <= cnt) {
            issue(B0, B1, B2, k + 1);
            compute(A0, A1, A2, k);
            if (k + 2 < cnt) issue(A0, A1, A2, k + 2);
            compute(B0, B1, B2, k + 1);
            k += 2;
        }
        if (k < cnt) compute(A0, A1, A2, k);
    }

    out_s[(size_t)node * F + fb] = sf[(size_t)node * F + fb] + acc_s;
    const float* vfi = vf + (size_t)node * F3 + fb * 3;
    float* ovi = out_v + (size_t)node * F3 + fb * 3;
    ovi[0] = vfi[0] + av0;
    ovi[1] = vfi[1] + av1;
    ovi[2] = vfi[2] + av2;
}

// ---------------- tiny-ws fallback ----------------
__global__ void transpose_wr(const float* __restrict__ Wr, float* __restrict__ WrT) {
    int idx = blockIdx.x * blockDim.x + threadIdx.x;
    if (idx < F3 * NRBF) {
        int f = idx / NRBF, r = idx % NRBF;
        WrT[r * F3 + f] = Wr[idx];
    }
}

__global__ void init_out(const float* __restrict__ sf, const float* __restrict__ vf,
                         float* __restrict__ out, int n_scalar, int n_total) {
    int i = blockIdx.x * blockDim.x + threadIdx.x;
    int n4 = n_total >> 2;
    if (i < n4) {
        float4 v;
        int base = i << 2;
        if (base < n_scalar) v = ((const float4*)sf)[i];
        else                 v = ((const float4*)vf)[i - (n_scalar >> 2)];
        ((float4*)out)[i] = v;
    }
}

__launch_bounds__(256)
__global__ void phi32_kernel(const float* __restrict__ sf,
                             const float* __restrict__ W1, const float* __restrict__ b1,
                             const float* __restrict__ W2, const float* __restrict__ b2,
                             float* __restrict__ phi, int n_nodes) {
    __shared__ float xs[NPB][F];
    __shared__ float hs[NPB][F];
    int tid = threadIdx.x;
    int nb = blockIdx.x * NPB;
    for (int t = tid; t < NPB * F / 4; t += 256) {
        int n  = t / (F / 4);
        int k4 = t % (F / 4);
        float4 v = make_float4(0.f, 0.f, 0.f, 0.f);
        if (nb + n < n_nodes) v = ((const float4*)(sf + (size_t)(nb + n) * F))[k4];
        ((float4*)&xs[n][0])[k4] = v;
    }
    __syncthreads();
    {
        int f = tid & (F - 1);
        int half_ = tid >> 7;
        float acc[8];
#pragma unroll
        for (int nn = 0; nn < 8; nn++) acc[nn] = 0.f;
        const float* w1row = W1 + (size_t)f * F;
        for (int k = 0; k < F; k++) {
            float w = w1row[k];
#pragma unroll
            for (int nn = 0; nn < 8; nn++)
                acc[nn] += xs[half_ * 8 + nn][k] * w;
        }
        float b = b1[f];
#pragma unroll
        for (int nn = 0; nn < 8; nn++) {
            float v = acc[nn] + b;
            hs[half_ * 8 + nn][f] = v / (1.f + __expf(-v));
        }
    }
    __syncthreads();
    for (int f = tid; f < F3; f += 256) {
        float acc[NPB];
#pragma unroll
        for (int n = 0; n < NPB; n++) acc[n] = 0.f;
        const float* w2row = W2 + (size_t)f * F;
        for (int k = 0; k < F; k++) {
            float w = w2row[k];
#pragma unroll
            for (int n = 0; n < NPB; n++)
                acc[n] += hs[n][k] * w;
        }
        float b = b2[f];
        for (int n = 0; n < NPB; n++)
            if (nb + n < n_nodes)
                phi[(size_t)(nb + n) * F3 + f] = acc[n] + b;
    }
}

__launch_bounds__(256)
__global__ void edge_kernel(const int* __restrict__ idx_i, const int* __restrict__ idx_j,
                            const float* __restrict__ rel_dir, const float* __restrict__ rdc,
                            const float* __restrict__ rbf,
                            const float* __restrict__ vf,
                            const float* __restrict__ WrT, const float* __restrict__ br,
                            const float* __restrict__ phi,
                            float* __restrict__ out_s, float* __restrict__ out_v,
                            int n_edges) {
    int lane = threadIdx.x & 63;
    int e = (int)((blockIdx.x * (unsigned)blockDim.x + threadIdx.x) >> 6);
    if (e >= n_edges) return;
    int i = idx_i[e], j = idx_j[e];
    float rd = rdc[e];
    float d0 = rel_dir[e * 3 + 0], d1 = rel_dir[e * 3 + 1], d2 = rel_dir[e * 3 + 2];
    float rb[NRBF];
#pragma unroll
    for (int r = 0; r < NRBF; r++) rb[r] = rbf[(size_t)e * NRBF + r];
    const float* pj = phi + (size_t)j * F3;
    float pw[6];
#pragma unroll
    for (int q = 0; q < 6; q++) {
        int f = lane + 64 * q;
        float acc = br[f];
#pragma unroll
        for (int r = 0; r < NRBF; r++)
            acc += rb[r] * WrT[r * F3 + f];
        pw[q] = acc * rd * pj[f];
    }
    atomicAdd(&out_s[(size_t)i * F + lane],       pw[2]);
    atomicAdd(&out_s[(size_t)i * F + lane + 64],  pw[3]);
    const float* vfj = vf + (size_t)j * F * 3;
    float* ovi = out_v + (size_t)i * F * 3;
#pragma unroll
    for (int h = 0; h < 2; h++) {
        int f = lane + 64 * h;
        float vv = pw[h];
        float vs = pw[4 + h];
        atomicAdd(&ovi[f * 3 + 0], vfj[f * 3 + 0] * vv + vs * d0);
        atomicAdd(&ovi[f * 3 + 1], vfj[f * 3 + 1] * vv + vs * d1);
        atomicAdd(&ovi[f * 3 + 2], vfj[f * 3 + 2] * vv + vs * d2);
    }
}

extern "C" void kernel_launch(void* const* d_in, const int* in_sizes, int n_in,
                              void* d_out, int out_size, void* d_ws, size_t ws_size,
                              hipStream_t stream) {
    const int*   idx_i   = (const int*)d_in[0];
    const int*   idx_j   = (const int*)d_in[1];
    const float* rel_dir = (const float*)d_in[2];
    const float* rdc     = (const float*)d_in[3];
    const float* rbf     = (const float*)d_in[4];
    const float* sf      = (const float*)d_in[5];
    const float* vf      = (const float*)d_in[6];
    const float* W1      = (const float*)d_in[7];
    const float* b1      = (const float*)d_in[8];
    const float* W2      = (const float*)d_in[9];
    const float* b2      = (const float*)d_in[10];
    const float* Wr      = (const float*)d_in[11];
    const float* br      = (const float*)d_in[12];

    int E = in_sizes[0];
    int N = in_sizes[5] / F;

    float* out_s = (float*)d_out;
    float* out_v = out_s + (size_t)N * F;

    // ---- v5 layout: MFMA phi + records ----
    size_t off = 0;
    auto slab = [&](size_t bytes) { size_t o = off; off = (off + bytes + 255) & ~(size_t)255; return o; };
    size_t o_wrth = slab((size_t)10 * F3 * sizeof(u32));
    size_t o_wh   = slab((size_t)(F + F3) * F * sizeof(_Float16));
    size_t o_gbuf = slab((size_t)N * 768 * sizeof(__half));
    size_t o_cnt  = slab((size_t)N * sizeof(int));
    size_t o_row  = slab((size_t)(N + 1) * sizeof(int));
    size_t o_rec  = slab((size_t)E * 64);
    size_t need_v5 = off;

    // ---- v3 layout: MFMA phi + edge_order ----
    size_t off3 = 0;
    auto slab3 = [&](size_t bytes) { size_t o = off3; off3 = (off3 + bytes + 255) & ~(size_t)255; return o; };
    size_t t_wrth = slab3((size_t)10 * F3 * sizeof(u32));
    size_t t_wh   = slab3((size_t)(F + F3) * F * sizeof(_Float16));
    size_t t_gbuf = slab3((size_t)N * 768 * sizeof(__half));
    size_t t_cnt  = slab3((size_t)N * sizeof(int));
    size_t t_row  = slab3((size_t)(N + 1) * sizeof(int));
    size_t t_ord  = slab3((size_t)E * sizeof(int));
    size_t need_v3 = off3;

    int prep_threads = 10 * F3 + (F + F3) * F + N;
    int HB = (E + 255) / 256;
    int PHB = (N + 63) / 64;

    if (ws_size >= need_v5) {
        u32*      WrTh      = (u32*)((char*)d_ws + o_wrth);
        _Float16* Wh        = (_Float16*)((char*)d_ws + o_wh);
        __half*   gbufh     = (__half*)((char*)d_ws + o_gbuf);
        u32*      gbuf      = (u32*)gbufh;
        int*      counts    = (int*)((char*)d_ws + o_cnt);
        int*      cursor    = counts;
        int*      row_start = (int*)((char*)d_ws + o_row);
        u32*      recs      = (u32*)((char*)d_ws + o_rec);

        prep_kernel<<<(prep_threads + 255) / 256, 256, 0, stream>>>(Wr, W1, W2, WrTh, Wh, counts, N);
        fusedB2_kernel<<<PHB + HB, 256, 0, stream>>>(sf, Wh, b1, b2, vf, gbufh,
                                                     idx_i, counts, N, E, PHB);
        if (N <= SCAN_MAXN)
            scan_lds_kernel<<<1, SCAN_T, 0, stream>>>(counts, row_start, cursor, N);
        else
            scan_kernel<<<1, 1024, 0, stream>>>(counts, row_start, cursor, N);
        build_records<<<(E + 255) / 256, 256, 0, stream>>>(idx_i, idx_j, rel_dir, rdc, rbf,
                                                           cursor, recs, E);
        gather5_kernel<<<(N + 1) / 2, 256, 0, stream>>>(sf, vf, WrTh, br, gbuf, recs,
                                                        row_start, out_s, out_v, N);
    } else if (ws_size >= need_v3) {
        u32*      WrTh      = (u32*)((char*)d_ws + t_wrth);
        _Float16* Wh        = (_Float16*)((char*)d_ws + t_wh);
        __half*   gbufh     = (__half*)((char*)d_ws + t_gbuf);
        u32*      gbuf      = (u32*)gbufh;
        int*      counts    = (int*)((char*)d_ws + t_cnt);
        int*      cursor    = counts;
        int*      row_start = (int*)((char*)d_ws + t_row);
        int*      edge_ord  = (int*)((char*)d_ws + t_ord);

        prep_kernel<<<(prep_threads + 255) / 256, 256, 0, stream>>>(Wr, W1, W2, WrTh, Wh, counts, N);
        fusedB2_kernel<<<PHB + HB, 256, 0, stream>>>(sf, Wh, b1, b2, vf, gbufh,
                                                     idx_i, counts, N, E, PHB);
        if (N <= SCAN_MAXN)
            scan_lds_kernel<<<1, SCAN_T, 0, stream>>>(counts, row_start, cursor, N);
        else
            scan_kernel<<<1, 1024, 0, stream>>>(counts, row_start, cursor, N);
        scatter_kernel<<<(E + 255) / 256, 256, 0, stream>>>(idx_i, cursor, edge_ord, E);
        gather3_kernel<<<(N + 1) / 2, 256, 0, stream>>>(idx_j, rel_dir, rdc, rbf, sf, vf,
                                                        WrTh, br, gbuf, row_start, edge_ord,
                                                        out_s, out_v, N);
    } else {
        size_t off2 = 0;
        auto slab2 = [&](size_t bytes) { size_t o = off2; off2 = (off2 + bytes + 255) & ~(size_t)255; return o; };
        size_t f_wrt = slab2((size_t)F3 * NRBF * sizeof(float));
        size_t f_phi = slab2((size_t)N * F3 * sizeof(float));
        float* WrT = (float*)((char*)d_ws + f_wrt);
        float* phi = (float*)((char*)d_ws + f_phi);

        int n_scalar = N * F;
        int n_total  = N * F * 4;
        init_out<<<(n_total / 4 + 255) / 256, 256, 0, stream>>>(sf, vf, (float*)d_out, n_scalar, n_total);
        transpose_wr<<<(F3 * NRBF + 255) / 256, 256, 0, stream>>>(Wr, WrT);
        phi32_kernel<<<(N + NPB - 1) / NPB, 256, 0, stream>>>(sf, W1, b1, W2, b2, phi, N);
        edge_kernel<<<(E + 3) / 4, 256, 0, stream>>>(idx_i, idx_j, rel_dir, rdc, rbf,
                                                     vf, WrT, br, phi, out_s, out_v, E);
    }
}